// Round 1
// baseline (1987.781 us; speedup 1.0000x reference)
//
#include <hip/hip_runtime.h>
#include <hip/hip_bf16.h>

// MoE SwiGLU MLP, sparse top-2 path.
// T=2048 tokens, D_MODEL=1024, D_FF=2048, E=8 experts, K=2.
// Pipeline: memset(64B) -> convert x to bf16 -> router -> base/loss ->
//   stageA grouped GEMM (x @ [Wg|Wu] -> silu(g)*u -> h bf16) ->
//   stageB grouped GEMM (h @ Wd + bd -> per-pair fp32) -> combine (weighted sum).

#define D_MODEL 1024
#define D_FF    2048
#define N_EXP   8
#define T_TOK   2048

typedef __attribute__((ext_vector_type(8))) short bf16x8;
typedef __attribute__((ext_vector_type(4))) float f32x4;

__device__ __forceinline__ ushort f2bf(float f) {
    union { float f; unsigned u; } c; c.f = f;
    unsigned u = c.u;
    return (ushort)((u + 0x7fffu + ((u >> 16) & 1u)) >> 16);  // RTNE
}

// ---------------- x fp32 -> bf16 ----------------
__global__ void k_convert_x(const float* __restrict__ x, ushort* __restrict__ xb) {
    int idx = blockIdx.x * 256 + threadIdx.x;          // 524288 float4s
    float4 v = ((const float4*)x)[idx];
    ushort4 o;
    o.x = f2bf(v.x); o.y = f2bf(v.y); o.z = f2bf(v.z); o.w = f2bf(v.w);
    ((ushort4*)xb)[idx] = o;
}

// ---------------- router: logits, softmax, top-2, slot assignment ----------------
__global__ __launch_bounds__(256) void k_router(
    const float* __restrict__ x, const float* __restrict__ gw, const float* __restrict__ gb,
    int* cnt, float* probsum, int* tok, int* slotpk, float* wtok)
{
    __shared__ float gws[N_EXP * D_MODEL];   // 32 KB
    int tid = threadIdx.x;
    for (int i = tid; i < N_EXP * D_MODEL / 4; i += 256)
        ((float4*)gws)[i] = ((const float4*)gw)[i];
    __syncthreads();

    int wave = tid >> 6, lane = tid & 63;
    int t = blockIdx.x * 4 + wave;           // one wave per token
    const float4* xr = (const float4*)(x + (size_t)t * D_MODEL);

    float acc[N_EXP];
#pragma unroll
    for (int e = 0; e < N_EXP; e++) acc[e] = 0.f;
#pragma unroll
    for (int q = 0; q < 4; q++) {
        float4 xv = xr[lane * 4 + q];
#pragma unroll
        for (int e = 0; e < N_EXP; e++) {
            float4 gv = ((const float4*)(gws + e * D_MODEL))[lane * 4 + q];
            acc[e] += xv.x * gv.x + xv.y * gv.y + xv.z * gv.z + xv.w * gv.w;
        }
    }
#pragma unroll
    for (int off = 32; off > 0; off >>= 1) {
#pragma unroll
        for (int e = 0; e < N_EXP; e++) acc[e] += __shfl_xor(acc[e], off, 64);
    }
    if (lane == 0) {
        float l[N_EXP], m = -1e30f;
#pragma unroll
        for (int e = 0; e < N_EXP; e++) { l[e] = acc[e] + gb[e]; m = fmaxf(m, l[e]); }
        float p[N_EXP], s = 0.f;
#pragma unroll
        for (int e = 0; e < N_EXP; e++) { p[e] = expf(l[e] - m); s += p[e]; }
        float inv = 1.f / s;
#pragma unroll
        for (int e = 0; e < N_EXP; e++) { p[e] *= inv; atomicAdd(&probsum[e], p[e]); }
        // top-2, lowest index wins ties (matches lax.top_k)
        int i0 = 0; float v0 = p[0];
#pragma unroll
        for (int e = 1; e < N_EXP; e++) if (p[e] > v0) { v0 = p[e]; i0 = e; }
        int i1 = -1; float v1 = -1.f;
#pragma unroll
        for (int e = 0; e < N_EXP; e++) if (e != i0 && p[e] > v1) { v1 = p[e]; i1 = e; }
        float winv = 1.f / (v0 + v1);
        int p0 = atomicAdd(&cnt[i0], 1);
        int p1 = atomicAdd(&cnt[i1], 1);
        tok[i0 * T_TOK + p0] = t;
        tok[i1 * T_TOK + p1] = t;
        slotpk[t * 2 + 0] = (i0 << 16) | p0;
        slotpk[t * 2 + 1] = (i1 << 16) | p1;
        wtok[t * 2 + 0] = v0 * winv;
        wtok[t * 2 + 1] = v1 * winv;
    }
}

// ---------------- expert bases (prefix sum) + balance loss ----------------
__global__ void k_base_loss(const int* __restrict__ cnt, const float* __restrict__ probsum,
                            int* base, float* loss_out)
{
    if (threadIdx.x == 0 && blockIdx.x == 0) {
        int b = 0;
        float loss = 0.f;
        for (int e = 0; e < N_EXP; e++) {
            base[e] = b; b += cnt[e];
            float mean = probsum[e] * (1.0f / T_TOK);
            loss += 0.125f * (logf(0.125f) - logf(mean + 1e-9f));
        }
        *loss_out = loss;
    }
}

// ---------------- stage A: h = silu(x@Wg + bg) * (x@Wu + bu), gathered rows ----------------
// 128x128 tile, BK=64, 4 waves, dual accumulators (Wg and Wu share the A tile).
__global__ __launch_bounds__(256, 2) void k_expert_gu(
    const float* __restrict__ Wg, const float* __restrict__ Wu,
    const float* __restrict__ bg, const float* __restrict__ bu,
    const ushort* __restrict__ xb, const int* __restrict__ cnt,
    const int* __restrict__ base, const int* __restrict__ tok,
    ushort* __restrict__ h)
{
    int e = blockIdx.x >> 4, mtile = blockIdx.x & 15;
    int ne = cnt[e];
    int m0 = mtile * 128;
    if (m0 >= ne) return;                 // uniform per block
    int n0 = blockIdx.y * 128;
    int nb = base[e];

    __shared__ __align__(16) ushort As[128 * 88];     // stride 88: 16B aligned, 2-way banks
    __shared__ __align__(16) ushort Bg_s[64 * 128];   // k-inner-8 layout
    __shared__ __align__(16) ushort Bu_s[64 * 128];

    int tid = threadIdx.x;
    int lane = tid & 63, wave = tid >> 6;
    int wm = (wave & 1) * 64, wn = (wave >> 1) * 64;

    // A staging: thread -> (row, k-half)
    int arow = tid >> 1;
    int akh = (tid & 1) * 32;
    int atok = tok[e * T_TOK + min(m0 + arow, ne - 1)];
    const ushort* xrow = xb + (size_t)atok * D_MODEL;

    // W staging: thread -> (n, k-half); k-vectorized coalesced fp32 loads
    int wnl = tid & 127;
    int wkh = (tid >> 7) * 32;
    const float* gp = Wg + (size_t)e * D_MODEL * D_FF + (size_t)wkh * D_FF + n0 + wnl;
    const float* up = Wu + (size_t)e * D_MODEL * D_FF + (size_t)wkh * D_FF + n0 + wnl;

    f32x4 accg[4][4], accu[4][4];
#pragma unroll
    for (int i = 0; i < 4; i++)
#pragma unroll
        for (int j = 0; j < 4; j++) {
            accg[i][j] = (f32x4){0.f, 0.f, 0.f, 0.f};
            accu[i][j] = (f32x4){0.f, 0.f, 0.f, 0.f};
        }

    for (int kt = 0; kt < D_MODEL / 64; kt++) {
        int k0 = kt * 64;
        __syncthreads();
        // A tile: bf16 copy, 16B chunks
#pragma unroll
        for (int q = 0; q < 4; q++)
            *(uint4*)&As[arow * 88 + akh + q * 8] = *(const uint4*)&xrow[k0 + akh + q * 8];
        // B tiles: fp32 -> bf16, transpose into k-inner-8 layout
        const float* gpk = gp + (size_t)k0 * D_FF;
        const float* upk = up + (size_t)k0 * D_FF;
#pragma unroll
        for (int q = 0; q < 8; q++) {
            int kl = wkh + q * 4;
            int kb = kl >> 3, ko = kl & 7;
            float a0 = gpk[(size_t)(q * 4 + 0) * D_FF];
            float a1 = gpk[(size_t)(q * 4 + 1) * D_FF];
            float a2 = gpk[(size_t)(q * 4 + 2) * D_FF];
            float a3 = gpk[(size_t)(q * 4 + 3) * D_FF];
            ushort4 pk; pk.x = f2bf(a0); pk.y = f2bf(a1); pk.z = f2bf(a2); pk.w = f2bf(a3);
            *(ushort4*)&Bg_s[(kb * 128 + wnl) * 8 + ko] = pk;
            float b0 = upk[(size_t)(q * 4 + 0) * D_FF];
            float b1 = upk[(size_t)(q * 4 + 1) * D_FF];
            float b2 = upk[(size_t)(q * 4 + 2) * D_FF];
            float b3 = upk[(size_t)(q * 4 + 3) * D_FF];
            ushort4 pu; pu.x = f2bf(b0); pu.y = f2bf(b1); pu.z = f2bf(b2); pu.w = f2bf(b3);
            *(ushort4*)&Bu_s[(kb * 128 + wnl) * 8 + ko] = pu;
        }
        __syncthreads();
        // compute
#pragma unroll
        for (int ks = 0; ks < 2; ks++) {
            bf16x8 af[4];
            int arow_f = wm + (lane & 15);
            int akb = ks * 32 + (lane >> 4) * 8;
#pragma unroll
            for (int sm = 0; sm < 4; sm++)
                af[sm] = *(const bf16x8*)&As[(arow_f + sm * 16) * 88 + akb];
            int bkb = ks * 4 + (lane >> 4);
#pragma unroll
            for (int sn = 0; sn < 4; sn++) {
                int ncol = wn + sn * 16 + (lane & 15);
                bf16x8 bgf = *(const bf16x8*)&Bg_s[(bkb * 128 + ncol) * 8];
                bf16x8 buf = *(const bf16x8*)&Bu_s[(bkb * 128 + ncol) * 8];
#pragma unroll
                for (int sm = 0; sm < 4; sm++) {
                    accg[sm][sn] = __builtin_amdgcn_mfma_f32_16x16x32_bf16(af[sm], bgf, accg[sm][sn], 0, 0, 0);
                    accu[sm][sn] = __builtin_amdgcn_mfma_f32_16x16x32_bf16(af[sm], buf, accu[sm][sn], 0, 0, 0);
                }
            }
        }
    }
    // epilogue: silu(g)*u -> h (bf16). C/D: col=lane&15, row=(lane>>4)*4+r
    int rbase = wm + ((lane >> 4) << 2);
    int cbase = wn + (lane & 15);
#pragma unroll
    for (int sm = 0; sm < 4; sm++) {
#pragma unroll
        for (int r = 0; r < 4; r++) {
            int pos = m0 + rbase + sm * 16 + r;
            if (pos < ne) {
                size_t hb = (size_t)(nb + pos) * D_FF;
#pragma unroll
                for (int sn = 0; sn < 4; sn++) {
                    int col = n0 + cbase + sn * 16;
                    float g = accg[sm][sn][r] + bg[e * D_FF + col];
                    float u = accu[sm][sn][r] + bu[e * D_FF + col];
                    float hv = (g / (1.f + expf(-g))) * u;
                    h[hb + col] = f2bf(hv);
                }
            }
        }
    }
}

// ---------------- stage B: outp = h @ Wd + bd ----------------
__global__ __launch_bounds__(256, 2) void k_expert_down(
    const float* __restrict__ Wd, const float* __restrict__ bd,
    const ushort* __restrict__ h, const int* __restrict__ cnt,
    const int* __restrict__ base, float* __restrict__ outp)
{
    int e = blockIdx.x >> 4, mtile = blockIdx.x & 15;
    int ne = cnt[e];
    int m0 = mtile * 128;
    if (m0 >= ne) return;
    int n0 = blockIdx.y * 128;
    int nb = base[e];

    __shared__ __align__(16) ushort As[128 * 88];
    __shared__ __align__(16) ushort Bd_s[64 * 128];

    int tid = threadIdx.x;
    int lane = tid & 63, wave = tid >> 6;
    int wm = (wave & 1) * 64, wn = (wave >> 1) * 64;

    int arow = tid >> 1;
    int akh = (tid & 1) * 32;
    const ushort* hrow = h + (size_t)(nb + min(m0 + arow, ne - 1)) * D_FF;

    int wnl = tid & 127;
    int wkh = (tid >> 7) * 32;
    const float* dp = Wd + (size_t)e * D_FF * D_MODEL + (size_t)wkh * D_MODEL + n0 + wnl;

    f32x4 acc[4][4];
#pragma unroll
    for (int i = 0; i < 4; i++)
#pragma unroll
        for (int j = 0; j < 4; j++) acc[i][j] = (f32x4){0.f, 0.f, 0.f, 0.f};

    for (int kt = 0; kt < D_FF / 64; kt++) {
        int k0 = kt * 64;
        __syncthreads();
#pragma unroll
        for (int q = 0; q < 4; q++)
            *(uint4*)&As[arow * 88 + akh + q * 8] = *(const uint4*)&hrow[k0 + akh + q * 8];
        const float* dpk = dp + (size_t)k0 * D_MODEL;
#pragma unroll
        for (int q = 0; q < 8; q++) {
            int kl = wkh + q * 4;
            int kb = kl >> 3, ko = kl & 7;
            float a0 = dpk[(size_t)(q * 4 + 0) * D_MODEL];
            float a1 = dpk[(size_t)(q * 4 + 1) * D_MODEL];
            float a2 = dpk[(size_t)(q * 4 + 2) * D_MODEL];
            float a3 = dpk[(size_t)(q * 4 + 3) * D_MODEL];
            ushort4 pk; pk.x = f2bf(a0); pk.y = f2bf(a1); pk.z = f2bf(a2); pk.w = f2bf(a3);
            *(ushort4*)&Bd_s[(kb * 128 + wnl) * 8 + ko] = pk;
        }
        __syncthreads();
#pragma unroll
        for (int ks = 0; ks < 2; ks++) {
            bf16x8 af[4];
            int arow_f = wm + (lane & 15);
            int akb = ks * 32 + (lane >> 4) * 8;
#pragma unroll
            for (int sm = 0; sm < 4; sm++)
                af[sm] = *(const bf16x8*)&As[(arow_f + sm * 16) * 88 + akb];
            int bkb = ks * 4 + (lane >> 4);
#pragma unroll
            for (int sn = 0; sn < 4; sn++) {
                int ncol = wn + sn * 16 + (lane & 15);
                bf16x8 bdf = *(const bf16x8*)&Bd_s[(bkb * 128 + ncol) * 8];
#pragma unroll
                for (int sm = 0; sm < 4; sm++)
                    acc[sm][sn] = __builtin_amdgcn_mfma_f32_16x16x32_bf16(af[sm], bdf, acc[sm][sn], 0, 0, 0);
            }
        }
    }
    int rbase = wm + ((lane >> 4) << 2);
    int cbase = wn + (lane & 15);
#pragma unroll
    for (int sm = 0; sm < 4; sm++) {
#pragma unroll
        for (int r = 0; r < 4; r++) {
            int pos = m0 + rbase + sm * 16 + r;
            if (pos < ne) {
                size_t ob = (size_t)(nb + pos) * D_MODEL;
#pragma unroll
                for (int sn = 0; sn < 4; sn++) {
                    int col = n0 + cbase + sn * 16;
                    outp[ob + col] = acc[sm][sn][r] + bd[e * D_MODEL + col];
                }
            }
        }
    }
}

// ---------------- combine: y[t] = w0*outp[slot0] + w1*outp[slot1] ----------------
__global__ void k_combine(const float* __restrict__ outp, const int* __restrict__ slotpk,
                          const float* __restrict__ wtok, const int* __restrict__ base,
                          float* __restrict__ y)
{
    int idx = blockIdx.x * 256 + threadIdx.x;   // 524288 float4s
    int t = idx >> 8, j = idx & 255;
    int sp0 = slotpk[t * 2 + 0], sp1 = slotpk[t * 2 + 1];
    float w0 = wtok[t * 2 + 0], w1 = wtok[t * 2 + 1];
    size_t s0 = (size_t)base[sp0 >> 16] + (sp0 & 0xffff);
    size_t s1 = (size_t)base[sp1 >> 16] + (sp1 & 0xffff);
    float4 a = ((const float4*)outp)[s0 * (D_MODEL / 4) + j];
    float4 b = ((const float4*)outp)[s1 * (D_MODEL / 4) + j];
    float4 o;
    o.x = w0 * a.x + w1 * b.x;
    o.y = w0 * a.y + w1 * b.y;
    o.z = w0 * a.z + w1 * b.z;
    o.w = w0 * a.w + w1 * b.w;
    ((float4*)y)[idx] = o;
}

extern "C" void kernel_launch(void* const* d_in, const int* in_sizes, int n_in,
                              void* d_out, int out_size, void* d_ws, size_t ws_size,
                              hipStream_t stream)
{
    const float* x  = (const float*)d_in[0];
    const float* gw = (const float*)d_in[1];
    const float* gb = (const float*)d_in[2];
    const float* Wg = (const float*)d_in[3];
    const float* bg = (const float*)d_in[4];
    const float* Wu = (const float*)d_in[5];
    const float* bu = (const float*)d_in[6];
    const float* Wd = (const float*)d_in[7];
    const float* bd = (const float*)d_in[8];
    float* y = (float*)d_out;
    float* loss_out = y + (size_t)T_TOK * D_MODEL;

    char* ws = (char*)d_ws;
    int*    cnt     = (int*)(ws + 0);           // 8 ints   [zeroed]
    float*  probsum = (float*)(ws + 32);        // 8 floats [zeroed]
    int*    base    = (int*)(ws + 64);          // 8 ints
    int*    slotpk  = (int*)(ws + 128);         // 4096 ints
    float*  wtok    = (float*)(ws + 16512);     // 4096 floats
    int*    tok     = (int*)(ws + 32896);       // 8*2048 ints
    ushort* xb      = (ushort*)(ws + 102400);   // 2M bf16 = 4 MB
    ushort* h       = (ushort*)(ws + 4296704);  // 4096*2048 bf16 = 16 MB
    float*  outp    = (float*)(ws + 21073920);  // 4096*1024 fp32 = 16 MB
    // total ws use: ~36.1 MB

    hipMemsetAsync(d_ws, 0, 64, stream);
    k_convert_x<<<dim3(2048), dim3(256), 0, stream>>>(x, xb);
    k_router<<<dim3(512), dim3(256), 0, stream>>>(x, gw, gb, cnt, probsum, tok, slotpk, wtok);
    k_base_loss<<<dim3(1), dim3(64), 0, stream>>>(cnt, probsum, base, loss_out);
    k_expert_gu<<<dim3(128, 16), dim3(256), 0, stream>>>(Wg, Wu, bg, bu, xb, cnt, base, tok, h);
    k_expert_down<<<dim3(128, 8), dim3(256), 0, stream>>>(Wd, bd, h, cnt, base, outp);
    k_combine<<<dim3(2048), dim3(256), 0, stream>>>(outp, slotpk, wtok, base, y);
}

// Round 2
// 1204.756 us; speedup vs baseline: 1.6499x; 1.6499x over previous
//
#include <hip/hip_runtime.h>
#include <hip/hip_bf16.h>

// MoE SwiGLU MLP, sparse top-2 path.
// T=2048 tokens, D_MODEL=1024, D_FF=2048, E=8 experts, K=2.
// R1: compacted expert-tile table (device-built) replaces the (e,mtile) grid
//     whose periodic dead-block pattern (x%16<4 active) aliased with the
//     32-SE round-robin distributor, parking 3/4 of the CUs.

#define D_MODEL 1024
#define D_FF    2048
#define N_EXP   8
#define T_TOK   2048
#define MAXTILES 40   // sum_e ceil(cnt_e/128) <= 32+7 < 40 (total rows always 4096)

typedef __attribute__((ext_vector_type(8))) short bf16x8;
typedef __attribute__((ext_vector_type(4))) float f32x4;

__device__ __forceinline__ ushort f2bf(float f) {
    union { float f; unsigned u; } c; c.f = f;
    unsigned u = c.u;
    return (ushort)((u + 0x7fffu + ((u >> 16) & 1u)) >> 16);  // RTNE
}

// ---------------- x fp32 -> bf16 ----------------
__global__ void k_convert_x(const float* __restrict__ x, ushort* __restrict__ xb) {
    int idx = blockIdx.x * 256 + threadIdx.x;          // 524288 float4s
    float4 v = ((const float4*)x)[idx];
    ushort4 o;
    o.x = f2bf(v.x); o.y = f2bf(v.y); o.z = f2bf(v.z); o.w = f2bf(v.w);
    ((ushort4*)xb)[idx] = o;
}

// ---------------- router: logits, softmax, top-2, slot assignment ----------------
__global__ __launch_bounds__(256) void k_router(
    const float* __restrict__ x, const float* __restrict__ gw, const float* __restrict__ gb,
    int* cnt, float* probsum, int* tok, int* slotpk, float* wtok)
{
    __shared__ float gws[N_EXP * D_MODEL];   // 32 KB
    int tid = threadIdx.x;
    for (int i = tid; i < N_EXP * D_MODEL / 4; i += 256)
        ((float4*)gws)[i] = ((const float4*)gw)[i];
    __syncthreads();

    int wave = tid >> 6, lane = tid & 63;
    int t = blockIdx.x * 4 + wave;           // one wave per token
    const float4* xr = (const float4*)(x + (size_t)t * D_MODEL);

    float acc[N_EXP];
#pragma unroll
    for (int e = 0; e < N_EXP; e++) acc[e] = 0.f;
#pragma unroll
    for (int q = 0; q < 4; q++) {
        float4 xv = xr[lane * 4 + q];
#pragma unroll
        for (int e = 0; e < N_EXP; e++) {
            float4 gv = ((const float4*)(gws + e * D_MODEL))[lane * 4 + q];
            acc[e] += xv.x * gv.x + xv.y * gv.y + xv.z * gv.z + xv.w * gv.w;
        }
    }
#pragma unroll
    for (int off = 32; off > 0; off >>= 1) {
#pragma unroll
        for (int e = 0; e < N_EXP; e++) acc[e] += __shfl_xor(acc[e], off, 64);
    }
    if (lane == 0) {
        float l[N_EXP], m = -1e30f;
#pragma unroll
        for (int e = 0; e < N_EXP; e++) { l[e] = acc[e] + gb[e]; m = fmaxf(m, l[e]); }
        float p[N_EXP], s = 0.f;
#pragma unroll
        for (int e = 0; e < N_EXP; e++) { p[e] = expf(l[e] - m); s += p[e]; }
        float inv = 1.f / s;
#pragma unroll
        for (int e = 0; e < N_EXP; e++) { p[e] *= inv; atomicAdd(&probsum[e], p[e]); }
        // top-2, lowest index wins ties (matches lax.top_k)
        int i0 = 0; float v0 = p[0];
#pragma unroll
        for (int e = 1; e < N_EXP; e++) if (p[e] > v0) { v0 = p[e]; i0 = e; }
        int i1 = -1; float v1 = -1.f;
#pragma unroll
        for (int e = 0; e < N_EXP; e++) if (e != i0 && p[e] > v1) { v1 = p[e]; i1 = e; }
        float winv = 1.f / (v0 + v1);
        int p0 = atomicAdd(&cnt[i0], 1);
        int p1 = atomicAdd(&cnt[i1], 1);
        tok[i0 * T_TOK + p0] = t;
        tok[i1 * T_TOK + p1] = t;
        slotpk[t * 2 + 0] = (i0 << 16) | p0;
        slotpk[t * 2 + 1] = (i1 << 16) | p1;
        wtok[t * 2 + 0] = v0 * winv;
        wtok[t * 2 + 1] = v1 * winv;
    }
}

// ---------------- expert bases (prefix sum) + tile table + balance loss ----------------
__global__ void k_base_loss(const int* __restrict__ cnt, const float* __restrict__ probsum,
                            int* base, int* tile, float* loss_out)
{
    if (threadIdx.x == 0 && blockIdx.x == 0) {
        int b = 0, nt = 0;
        float loss = 0.f;
        for (int e = 0; e < N_EXP; e++) {
            base[e] = b; b += cnt[e];
            for (int m0 = 0; m0 < cnt[e]; m0 += 128)
                tile[nt++] = (e << 16) | m0;
            float mean = probsum[e] * (1.0f / T_TOK);
            loss += 0.125f * (logf(0.125f) - logf(mean + 1e-9f));
        }
        for (; nt < MAXTILES; nt++) tile[nt] = -1;
        *loss_out = loss;
    }
}

// ---------------- stage A: h = silu(x@Wg + bg) * (x@Wu + bu), gathered rows ----------------
// 128x128 tile, BK=64, 4 waves, dual accumulators (Wg and Wu share the A tile).
__global__ __launch_bounds__(256, 2) void k_expert_gu(
    const float* __restrict__ Wg, const float* __restrict__ Wu,
    const float* __restrict__ bg, const float* __restrict__ bu,
    const ushort* __restrict__ xb, const int* __restrict__ cnt,
    const int* __restrict__ base, const int* __restrict__ tile,
    const int* __restrict__ tok, ushort* __restrict__ h)
{
    int ti = tile[blockIdx.x];
    if (ti < 0) return;                       // contiguous tail only
    int e = ti >> 16, m0 = ti & 0xffff;
    int ne = cnt[e];
    int n0 = blockIdx.y * 128;
    int nb = base[e];

    __shared__ __align__(16) ushort As[128 * 88];     // stride 88: 16B aligned, 2-way banks
    __shared__ __align__(16) ushort Bg_s[64 * 128];   // k-inner-8 layout
    __shared__ __align__(16) ushort Bu_s[64 * 128];

    int tid = threadIdx.x;
    int lane = tid & 63, wave = tid >> 6;
    int wm = (wave & 1) * 64, wn = (wave >> 1) * 64;

    // A staging: thread -> (row, k-half)
    int arow = tid >> 1;
    int akh = (tid & 1) * 32;
    int atok = tok[e * T_TOK + min(m0 + arow, ne - 1)];
    const ushort* xrow = xb + (size_t)atok * D_MODEL;

    // W staging: thread -> (n, k-half); k-vectorized coalesced fp32 loads
    int wnl = tid & 127;
    int wkh = (tid >> 7) * 32;
    const float* gp = Wg + (size_t)e * D_MODEL * D_FF + (size_t)wkh * D_FF + n0 + wnl;
    const float* up = Wu + (size_t)e * D_MODEL * D_FF + (size_t)wkh * D_FF + n0 + wnl;

    f32x4 accg[4][4], accu[4][4];
#pragma unroll
    for (int i = 0; i < 4; i++)
#pragma unroll
        for (int j = 0; j < 4; j++) {
            accg[i][j] = (f32x4){0.f, 0.f, 0.f, 0.f};
            accu[i][j] = (f32x4){0.f, 0.f, 0.f, 0.f};
        }

    for (int kt = 0; kt < D_MODEL / 64; kt++) {
        int k0 = kt * 64;
        __syncthreads();
        // A tile: bf16 copy, 16B chunks
#pragma unroll
        for (int q = 0; q < 4; q++)
            *(uint4*)&As[arow * 88 + akh + q * 8] = *(const uint4*)&xrow[k0 + akh + q * 8];
        // B tiles: fp32 -> bf16, transpose into k-inner-8 layout
        const float* gpk = gp + (size_t)k0 * D_FF;
        const float* upk = up + (size_t)k0 * D_FF;
#pragma unroll
        for (int q = 0; q < 8; q++) {
            int kl = wkh + q * 4;
            int kb = kl >> 3, ko = kl & 7;
            float a0 = gpk[(size_t)(q * 4 + 0) * D_FF];
            float a1 = gpk[(size_t)(q * 4 + 1) * D_FF];
            float a2 = gpk[(size_t)(q * 4 + 2) * D_FF];
            float a3 = gpk[(size_t)(q * 4 + 3) * D_FF];
            ushort4 pk; pk.x = f2bf(a0); pk.y = f2bf(a1); pk.z = f2bf(a2); pk.w = f2bf(a3);
            *(ushort4*)&Bg_s[(kb * 128 + wnl) * 8 + ko] = pk;
            float b0 = upk[(size_t)(q * 4 + 0) * D_FF];
            float b1 = upk[(size_t)(q * 4 + 1) * D_FF];
            float b2 = upk[(size_t)(q * 4 + 2) * D_FF];
            float b3 = upk[(size_t)(q * 4 + 3) * D_FF];
            ushort4 pu; pu.x = f2bf(b0); pu.y = f2bf(b1); pu.z = f2bf(b2); pu.w = f2bf(b3);
            *(ushort4*)&Bu_s[(kb * 128 + wnl) * 8 + ko] = pu;
        }
        __syncthreads();
        // compute
#pragma unroll
        for (int ks = 0; ks < 2; ks++) {
            bf16x8 af[4];
            int arow_f = wm + (lane & 15);
            int akb = ks * 32 + (lane >> 4) * 8;
#pragma unroll
            for (int sm = 0; sm < 4; sm++)
                af[sm] = *(const bf16x8*)&As[(arow_f + sm * 16) * 88 + akb];
            int bkb = ks * 4 + (lane >> 4);
#pragma unroll
            for (int sn = 0; sn < 4; sn++) {
                int ncol = wn + sn * 16 + (lane & 15);
                bf16x8 bgf = *(const bf16x8*)&Bg_s[(bkb * 128 + ncol) * 8];
                bf16x8 buf = *(const bf16x8*)&Bu_s[(bkb * 128 + ncol) * 8];
#pragma unroll
                for (int sm = 0; sm < 4; sm++) {
                    accg[sm][sn] = __builtin_amdgcn_mfma_f32_16x16x32_bf16(af[sm], bgf, accg[sm][sn], 0, 0, 0);
                    accu[sm][sn] = __builtin_amdgcn_mfma_f32_16x16x32_bf16(af[sm], buf, accu[sm][sn], 0, 0, 0);
                }
            }
        }
    }
    // epilogue: silu(g)*u -> h (bf16). C/D: col=lane&15, row=(lane>>4)*4+r
    int rbase = wm + ((lane >> 4) << 2);
    int cbase = wn + (lane & 15);
#pragma unroll
    for (int sm = 0; sm < 4; sm++) {
#pragma unroll
        for (int r = 0; r < 4; r++) {
            int pos = m0 + rbase + sm * 16 + r;
            if (pos < ne) {
                size_t hb = (size_t)(nb + pos) * D_FF;
#pragma unroll
                for (int sn = 0; sn < 4; sn++) {
                    int col = n0 + cbase + sn * 16;
                    float g = accg[sm][sn][r] + bg[e * D_FF + col];
                    float u = accu[sm][sn][r] + bu[e * D_FF + col];
                    float hv = (g / (1.f + expf(-g))) * u;
                    h[hb + col] = f2bf(hv);
                }
            }
        }
    }
}

// ---------------- stage B: outp = h @ Wd + bd ----------------
__global__ __launch_bounds__(256, 2) void k_expert_down(
    const float* __restrict__ Wd, const float* __restrict__ bd,
    const ushort* __restrict__ h, const int* __restrict__ cnt,
    const int* __restrict__ base, const int* __restrict__ tile,
    float* __restrict__ outp)
{
    int ti = tile[blockIdx.x];
    if (ti < 0) return;
    int e = ti >> 16, m0 = ti & 0xffff;
    int ne = cnt[e];
    int n0 = blockIdx.y * 128;
    int nb = base[e];

    __shared__ __align__(16) ushort As[128 * 88];
    __shared__ __align__(16) ushort Bd_s[64 * 128];

    int tid = threadIdx.x;
    int lane = tid & 63, wave = tid >> 6;
    int wm = (wave & 1) * 64, wn = (wave >> 1) * 64;

    int arow = tid >> 1;
    int akh = (tid & 1) * 32;
    const ushort* hrow = h + (size_t)(nb + min(m0 + arow, ne - 1)) * D_FF;

    int wnl = tid & 127;
    int wkh = (tid >> 7) * 32;
    const float* dp = Wd + (size_t)e * D_FF * D_MODEL + (size_t)wkh * D_MODEL + n0 + wnl;

    f32x4 acc[4][4];
#pragma unroll
    for (int i = 0; i < 4; i++)
#pragma unroll
        for (int j = 0; j < 4; j++) acc[i][j] = (f32x4){0.f, 0.f, 0.f, 0.f};

    for (int kt = 0; kt < D_FF / 64; kt++) {
        int k0 = kt * 64;
        __syncthreads();
#pragma unroll
        for (int q = 0; q < 4; q++)
            *(uint4*)&As[arow * 88 + akh + q * 8] = *(const uint4*)&hrow[k0 + akh + q * 8];
        const float* dpk = dp + (size_t)k0 * D_MODEL;
#pragma unroll
        for (int q = 0; q < 8; q++) {
            int kl = wkh + q * 4;
            int kb = kl >> 3, ko = kl & 7;
            float a0 = dpk[(size_t)(q * 4 + 0) * D_MODEL];
            float a1 = dpk[(size_t)(q * 4 + 1) * D_MODEL];
            float a2 = dpk[(size_t)(q * 4 + 2) * D_MODEL];
            float a3 = dpk[(size_t)(q * 4 + 3) * D_MODEL];
            ushort4 pk; pk.x = f2bf(a0); pk.y = f2bf(a1); pk.z = f2bf(a2); pk.w = f2bf(a3);
            *(ushort4*)&Bd_s[(kb * 128 + wnl) * 8 + ko] = pk;
        }
        __syncthreads();
#pragma unroll
        for (int ks = 0; ks < 2; ks++) {
            bf16x8 af[4];
            int arow_f = wm + (lane & 15);
            int akb = ks * 32 + (lane >> 4) * 8;
#pragma unroll
            for (int sm = 0; sm < 4; sm++)
                af[sm] = *(const bf16x8*)&As[(arow_f + sm * 16) * 88 + akb];
            int bkb = ks * 4 + (lane >> 4);
#pragma unroll
            for (int sn = 0; sn < 4; sn++) {
                int ncol = wn + sn * 16 + (lane & 15);
                bf16x8 bdf = *(const bf16x8*)&Bd_s[(bkb * 128 + ncol) * 8];
#pragma unroll
                for (int sm = 0; sm < 4; sm++)
                    acc[sm][sn] = __builtin_amdgcn_mfma_f32_16x16x32_bf16(af[sm], bdf, acc[sm][sn], 0, 0, 0);
            }
        }
    }
    int rbase = wm + ((lane >> 4) << 2);
    int cbase = wn + (lane & 15);
#pragma unroll
    for (int sm = 0; sm < 4; sm++) {
#pragma unroll
        for (int r = 0; r < 4; r++) {
            int pos = m0 + rbase + sm * 16 + r;
            if (pos < ne) {
                size_t ob = (size_t)(nb + pos) * D_MODEL;
#pragma unroll
                for (int sn = 0; sn < 4; sn++) {
                    int col = n0 + cbase + sn * 16;
                    outp[ob + col] = acc[sm][sn][r] + bd[e * D_MODEL + col];
                }
            }
        }
    }
}

// ---------------- combine: y[t] = w0*outp[slot0] + w1*outp[slot1] ----------------
__global__ void k_combine(const float* __restrict__ outp, const int* __restrict__ slotpk,
                          const float* __restrict__ wtok, const int* __restrict__ base,
                          float* __restrict__ y)
{
    int idx = blockIdx.x * 256 + threadIdx.x;   // 524288 float4s
    int t = idx >> 8, j = idx & 255;
    int sp0 = slotpk[t * 2 + 0], sp1 = slotpk[t * 2 + 1];
    float w0 = wtok[t * 2 + 0], w1 = wtok[t * 2 + 1];
    size_t s0 = (size_t)base[sp0 >> 16] + (sp0 & 0xffff);
    size_t s1 = (size_t)base[sp1 >> 16] + (sp1 & 0xffff);
    float4 a = ((const float4*)outp)[s0 * (D_MODEL / 4) + j];
    float4 b = ((const float4*)outp)[s1 * (D_MODEL / 4) + j];
    float4 o;
    o.x = w0 * a.x + w1 * b.x;
    o.y = w0 * a.y + w1 * b.y;
    o.z = w0 * a.z + w1 * b.z;
    o.w = w0 * a.w + w1 * b.w;
    ((float4*)y)[idx] = o;
}

extern "C" void kernel_launch(void* const* d_in, const int* in_sizes, int n_in,
                              void* d_out, int out_size, void* d_ws, size_t ws_size,
                              hipStream_t stream)
{
    const float* x  = (const float*)d_in[0];
    const float* gw = (const float*)d_in[1];
    const float* gb = (const float*)d_in[2];
    const float* Wg = (const float*)d_in[3];
    const float* bg = (const float*)d_in[4];
    const float* Wu = (const float*)d_in[5];
    const float* bu = (const float*)d_in[6];
    const float* Wd = (const float*)d_in[7];
    const float* bd = (const float*)d_in[8];
    float* y = (float*)d_out;
    float* loss_out = y + (size_t)T_TOK * D_MODEL;

    char* ws = (char*)d_ws;
    int*    cnt     = (int*)(ws + 0);           // 8 ints   [zeroed]
    float*  probsum = (float*)(ws + 32);        // 8 floats [zeroed]
    int*    base    = (int*)(ws + 64);          // 8 ints
    int*    tiletab = (int*)(ws + 96);          // MAXTILES ints (40 -> 160 B)
    int*    slotpk  = (int*)(ws + 512);         // 4096 ints = 16 KB
    float*  wtok    = (float*)(ws + 16896);     // 4096 floats = 16 KB
    int*    tok     = (int*)(ws + 33280);       // 8*2048 ints = 64 KB
    ushort* xb      = (ushort*)(ws + 102400);   // 2M bf16 = 4 MB
    ushort* h       = (ushort*)(ws + 4296704);  // 4096*2048 bf16 = 16 MB
    float*  outp    = (float*)(ws + 21073920);  // 4096*1024 fp32 = 16 MB
    // total ws use: ~36.1 MB

    hipMemsetAsync(d_ws, 0, 64, stream);
    k_convert_x<<<dim3(2048), dim3(256), 0, stream>>>(x, xb);
    k_router<<<dim3(512), dim3(256), 0, stream>>>(x, gw, gb, cnt, probsum, tok, slotpk, wtok);
    k_base_loss<<<dim3(1), dim3(64), 0, stream>>>(cnt, probsum, base, tiletab, loss_out);
    k_expert_gu<<<dim3(MAXTILES, 16), dim3(256), 0, stream>>>(Wg, Wu, bg, bu, xb, cnt, base, tiletab, tok, h);
    k_expert_down<<<dim3(MAXTILES, 8), dim3(256), 0, stream>>>(Wd, bd, h, cnt, base, tiletab, outp);
    k_combine<<<dim3(2048), dim3(256), 0, stream>>>(outp, slotpk, wtok, base, y);
}

// Round 3
// 621.998 us; speedup vs baseline: 3.1958x; 1.9369x over previous
//
#include <hip/hip_runtime.h>
#include <hip/hip_bf16.h>

// MoE SwiGLU MLP, sparse top-2 path.
// T=2048 tokens, D_MODEL=1024, D_FF=2048, E=8 experts, K=2.
// R2: weights pre-converted (fp32->bf16) and pre-tiled into MFMA-ready 16KB
//     k-inner-8 blocks by k_prep_w; GEMM staging is now pure global_load_lds
//     (no VGPR round-trip, no in-loop convert/transpose). h is produced in the
//     same tiled layout so stage B's A-operand is also a block copy.
//     Slot bases 128-aligned (capacity padding) so all tile copies contiguous.

#define D_MODEL 1024
#define D_FF    2048
#define N_EXP   8
#define T_TOK   2048
#define MAXTILES 40   // sum_e ceil(cnt_e/128) <= 32+7 < 40

typedef __attribute__((ext_vector_type(8))) short bf16x8;
typedef __attribute__((ext_vector_type(8))) ushort u16x8;
typedef __attribute__((ext_vector_type(4))) float f32x4;

__device__ __forceinline__ ushort f2bf(float f) {
    union { float f; unsigned u; } c; c.f = f;
    unsigned u = c.u;
    return (ushort)((u + 0x7fffu + ((u >> 16) & 1u)) >> 16);  // RTNE
}

__device__ __forceinline__ void glds16(const void* g, void* l) {
    __builtin_amdgcn_global_load_lds(
        (const __attribute__((address_space(1))) unsigned int*)g,
        (__attribute__((address_space(3))) unsigned int*)l, 16, 0, 0);
}

// ---------------- x fp32 -> bf16 ----------------
__global__ void k_convert_x(const float* __restrict__ x, ushort* __restrict__ xb) {
    int idx = blockIdx.x * 256 + threadIdx.x;          // 524288 float4s
    float4 v = ((const float4*)x)[idx];
    ushort4 o;
    o.x = f2bf(v.x); o.y = f2bf(v.y); o.z = f2bf(v.z); o.w = f2bf(v.w);
    ((ushort4*)xb)[idx] = o;
}

// ---------------- weight prep: fp32 -> bf16, tiled k-inner-8 16KB blocks ----------------
// Tile = 64 k x 128 n. Layout within tile: [(kb)*128 + ncol]*8 + ko, k = kb*8+ko.
// Wg/Wu: (e, nt 0..15, kt 0..15), N=2048, K=1024. Wd: (e, nt 0..7, kt 0..31), N=1024, K=2048.
__global__ __launch_bounds__(256) void k_prep_w(
    const float* __restrict__ Wg, const float* __restrict__ Wu, const float* __restrict__ Wd,
    ushort* __restrict__ Wgt, ushort* __restrict__ Wut, ushort* __restrict__ Wdt)
{
    int t = blockIdx.x;          // 0..2047 (tile linear index == output block index)
    int which = blockIdx.y;      // 0=Wg 1=Wu 2=Wd
    const float* src; ushort* dst; int N, K, nt, kt;
    int e = t >> 8;
    if (which == 2) { src = Wd; dst = Wdt; N = 1024; K = 2048; nt = (t >> 5) & 7;  kt = t & 31; }
    else            { src = (which ? Wu : Wg); dst = (which ? Wut : Wgt); N = 2048; K = 1024; nt = (t >> 4) & 15; kt = t & 15; }

    int tid = threadIdx.x;
    int ncol = tid & 127, kbh = (tid >> 7) * 4;
    const float* colp = src + (size_t)e * K * N + (size_t)(kt * 64) * N + nt * 128 + ncol;
    ushort* dtile = dst + (size_t)t * 8192;
#pragma unroll
    for (int i = 0; i < 4; i++) {
        int kb = kbh + i;
        const float* p = colp + (size_t)(kb * 8) * N;
        u16x8 o;
#pragma unroll
        for (int j = 0; j < 8; j++) o[j] = f2bf(p[(size_t)j * N]);
        *(u16x8*)&dtile[(kb * 128 + ncol) * 8] = o;
    }
}

// ---------------- router: logits, softmax, top-2, slot assignment ----------------
__global__ __launch_bounds__(256) void k_router(
    const float* __restrict__ x, const float* __restrict__ gw, const float* __restrict__ gb,
    int* cnt, float* probsum, int* tok, int* slotpk, float* wtok)
{
    __shared__ float gws[N_EXP * D_MODEL];   // 32 KB
    int tid = threadIdx.x;
    for (int i = tid; i < N_EXP * D_MODEL / 4; i += 256)
        ((float4*)gws)[i] = ((const float4*)gw)[i];
    __syncthreads();

    int wave = tid >> 6, lane = tid & 63;
    int t = blockIdx.x * 4 + wave;           // one wave per token
    const float4* xr = (const float4*)(x + (size_t)t * D_MODEL);

    float acc[N_EXP];
#pragma unroll
    for (int e = 0; e < N_EXP; e++) acc[e] = 0.f;
#pragma unroll
    for (int q = 0; q < 4; q++) {
        float4 xv = xr[lane * 4 + q];
#pragma unroll
        for (int e = 0; e < N_EXP; e++) {
            float4 gv = ((const float4*)(gws + e * D_MODEL))[lane * 4 + q];
            acc[e] += xv.x * gv.x + xv.y * gv.y + xv.z * gv.z + xv.w * gv.w;
        }
    }
#pragma unroll
    for (int off = 32; off > 0; off >>= 1) {
#pragma unroll
        for (int e = 0; e < N_EXP; e++) acc[e] += __shfl_xor(acc[e], off, 64);
    }
    if (lane == 0) {
        float l[N_EXP], m = -1e30f;
#pragma unroll
        for (int e = 0; e < N_EXP; e++) { l[e] = acc[e] + gb[e]; m = fmaxf(m, l[e]); }
        float p[N_EXP], s = 0.f;
#pragma unroll
        for (int e = 0; e < N_EXP; e++) { p[e] = expf(l[e] - m); s += p[e]; }
        float inv = 1.f / s;
#pragma unroll
        for (int e = 0; e < N_EXP; e++) { p[e] *= inv; atomicAdd(&probsum[e], p[e]); }
        // top-2, lowest index wins ties (matches lax.top_k)
        int i0 = 0; float v0 = p[0];
#pragma unroll
        for (int e = 1; e < N_EXP; e++) if (p[e] > v0) { v0 = p[e]; i0 = e; }
        int i1 = -1; float v1 = -1.f;
#pragma unroll
        for (int e = 0; e < N_EXP; e++) if (e != i0 && p[e] > v1) { v1 = p[e]; i1 = e; }
        float winv = 1.f / (v0 + v1);
        int p0 = atomicAdd(&cnt[i0], 1);
        int p1 = atomicAdd(&cnt[i1], 1);
        tok[i0 * T_TOK + p0] = t;
        tok[i1 * T_TOK + p1] = t;
        slotpk[t * 2 + 0] = (i0 << 16) | p0;
        slotpk[t * 2 + 1] = (i1 << 16) | p1;
        wtok[t * 2 + 0] = v0 * winv;
        wtok[t * 2 + 1] = v1 * winv;
    }
}

// ---------------- 128-aligned expert bases + tile table + balance loss ----------------
__global__ void k_base_loss(const int* __restrict__ cnt, const float* __restrict__ probsum,
                            int* abase, int* tile, float* loss_out)
{
    if (threadIdx.x == 0 && blockIdx.x == 0) {
        int b = 0, nt = 0;
        float loss = 0.f;
        for (int e = 0; e < N_EXP; e++) {
            abase[e] = b;
            for (int m0 = 0; m0 < cnt[e]; m0 += 128)
                tile[nt++] = (e << 16) | m0;
            b += ((cnt[e] + 127) >> 7) * 128;           // capacity-aligned
            float mean = probsum[e] * (1.0f / T_TOK);
            loss += 0.125f * (logf(0.125f) - logf(mean + 1e-9f));
        }
        for (; nt < MAXTILES; nt++) tile[nt] = -1;
        *loss_out = loss;
    }
}

// ---------------- stage A: h = silu(x@Wg + bg) * (x@Wu + bu) ----------------
// 128x128 tile, BK=64, 4 waves, dual accumulators. B via global_load_lds from
// pre-tiled weights; A gathered (tok) with uint4 copies; h written tiled.
__global__ __launch_bounds__(256, 2) void k_expert_gu(
    const ushort* __restrict__ Wgt, const ushort* __restrict__ Wut,
    const float* __restrict__ bg, const float* __restrict__ bu,
    const ushort* __restrict__ xb, const int* __restrict__ cnt,
    const int* __restrict__ abase, const int* __restrict__ tile,
    const int* __restrict__ tok, ushort* __restrict__ h_t)
{
    int ti = tile[blockIdx.x];
    if (ti < 0) return;                       // contiguous tail only
    int e = ti >> 16, m0 = ti & 0xffff;
    int ne = cnt[e];
    int nt = blockIdx.y;                      // 0..15
    int n0 = nt * 128;
    int stile = (abase[e] >> 7) + (m0 >> 7);  // global aligned slot-tile

    __shared__ __align__(16) ushort As[128 * 88];     // stride 88: 16B aligned, 2-way banks
    __shared__ __align__(16) ushort Bg_s[8192];       // k-inner-8 image (16KB)
    __shared__ __align__(16) ushort Bu_s[8192];

    int tid = threadIdx.x;
    int lane = tid & 63, wave = tid >> 6;
    int wm = (wave & 1) * 64, wn = (wave >> 1) * 64;

    // A staging: thread -> (row, k-half)
    int arow = tid >> 1;
    int akh = (tid & 1) * 32;
    int atok = tok[e * T_TOK + min(m0 + arow, ne - 1)];
    const ushort* xrow = xb + (size_t)atok * D_MODEL;

    // B tile bases (16KB per kt)
    const char* gbase = (const char*)(Wgt + (size_t)(e * 16 + nt) * 16 * 8192);
    const char* ubase = (const char*)(Wut + (size_t)(e * 16 + nt) * 16 * 8192);
    int goff = tid * 16;                      // per-lane global byte offset in tile
    int loff = (tid >> 6) * 1024;             // wave-uniform LDS byte offset

    f32x4 accg[4][4], accu[4][4];
#pragma unroll
    for (int i = 0; i < 4; i++)
#pragma unroll
        for (int j = 0; j < 4; j++) {
            accg[i][j] = (f32x4){0.f, 0.f, 0.f, 0.f};
            accu[i][j] = (f32x4){0.f, 0.f, 0.f, 0.f};
        }

    for (int kt = 0; kt < D_MODEL / 64; kt++) {
        __syncthreads();
        // A tile: bf16 gather copy, 16B chunks
#pragma unroll
        for (int q = 0; q < 4; q++)
            *(uint4*)&As[arow * 88 + akh + q * 8] = *(const uint4*)&xrow[kt * 64 + akh + q * 8];
        // B tiles: direct-to-LDS block copy (16KB each)
        const char* gsrc = gbase + kt * 16384;
        const char* usrc = ubase + kt * 16384;
#pragma unroll
        for (int q = 0; q < 4; q++) {
            glds16(gsrc + q * 4096 + goff, (char*)Bg_s + q * 4096 + loff);
            glds16(usrc + q * 4096 + goff, (char*)Bu_s + q * 4096 + loff);
        }
        __syncthreads();
        // compute
#pragma unroll
        for (int ks = 0; ks < 2; ks++) {
            bf16x8 af[4];
            int arow_f = wm + (lane & 15);
            int akb = ks * 32 + (lane >> 4) * 8;
#pragma unroll
            for (int sm = 0; sm < 4; sm++)
                af[sm] = *(const bf16x8*)&As[(arow_f + sm * 16) * 88 + akb];
            int bkb = ks * 4 + (lane >> 4);
#pragma unroll
            for (int sn = 0; sn < 4; sn++) {
                int ncol = wn + sn * 16 + (lane & 15);
                bf16x8 bgf = *(const bf16x8*)&Bg_s[(bkb * 128 + ncol) * 8];
                bf16x8 buf = *(const bf16x8*)&Bu_s[(bkb * 128 + ncol) * 8];
#pragma unroll
                for (int sm = 0; sm < 4; sm++) {
                    accg[sm][sn] = __builtin_amdgcn_mfma_f32_16x16x32_bf16(af[sm], bgf, accg[sm][sn], 0, 0, 0);
                    accu[sm][sn] = __builtin_amdgcn_mfma_f32_16x16x32_bf16(af[sm], buf, accu[sm][sn], 0, 0, 0);
                }
            }
        }
    }
    // epilogue: silu(g)*u -> h_t (bf16, tiled k-inner-8 for stage B's A-operand)
    int rbase = wm + ((lane >> 4) << 2);
    int cbase = wn + (lane & 15);
    size_t tbase = (size_t)stile * 32 * 8192;
#pragma unroll
    for (int sm = 0; sm < 4; sm++) {
#pragma unroll
        for (int r = 0; r < 4; r++) {
            int pos = m0 + rbase + sm * 16 + r;
            if (pos < ne) {
                int row = pos & 127;
#pragma unroll
                for (int sn = 0; sn < 4; sn++) {
                    int col = n0 + cbase + sn * 16;
                    float g = accg[sm][sn][r] + bg[e * D_FF + col];
                    float u = accu[sm][sn][r] + bu[e * D_FF + col];
                    float hv = (g / (1.f + expf(-g))) * u;
                    int ktb = col >> 6, kb = (col >> 3) & 7, ko = col & 7;
                    h_t[tbase + (size_t)ktb * 8192 + (kb * 128 + row) * 8 + ko] = f2bf(hv);
                }
            }
        }
    }
}

// ---------------- stage B: outp = h @ Wd + bd (both operands via global_load_lds) ----------------
__global__ __launch_bounds__(256, 2) void k_expert_down(
    const ushort* __restrict__ Wdt, const float* __restrict__ bd,
    const ushort* __restrict__ h_t, const int* __restrict__ cnt,
    const int* __restrict__ abase, const int* __restrict__ tile,
    float* __restrict__ outp)
{
    int ti = tile[blockIdx.x];
    if (ti < 0) return;
    int e = ti >> 16, m0 = ti & 0xffff;
    int ne = cnt[e];
    int nt = blockIdx.y;                      // 0..7
    int n0 = nt * 128;
    int stile = (abase[e] >> 7) + (m0 >> 7);

    __shared__ __align__(16) ushort As8[8192];        // k-inner-8 image (16KB)
    __shared__ __align__(16) ushort Bd_s[8192];

    int tid = threadIdx.x;
    int lane = tid & 63, wave = tid >> 6;
    int wm = (wave & 1) * 64, wn = (wave >> 1) * 64;

    const char* hbase = (const char*)(h_t + (size_t)stile * 32 * 8192);
    const char* dbase = (const char*)(Wdt + (size_t)(e * 8 + nt) * 32 * 8192);
    int goff = tid * 16;
    int loff = (tid >> 6) * 1024;

    f32x4 acc[4][4];
#pragma unroll
    for (int i = 0; i < 4; i++)
#pragma unroll
        for (int j = 0; j < 4; j++) acc[i][j] = (f32x4){0.f, 0.f, 0.f, 0.f};

    for (int kt = 0; kt < D_FF / 64; kt++) {
        __syncthreads();
        const char* asrc = hbase + kt * 16384;
        const char* bsrc = dbase + kt * 16384;
#pragma unroll
        for (int q = 0; q < 4; q++) {
            glds16(asrc + q * 4096 + goff, (char*)As8 + q * 4096 + loff);
            glds16(bsrc + q * 4096 + goff, (char*)Bd_s + q * 4096 + loff);
        }
        __syncthreads();
#pragma unroll
        for (int ks = 0; ks < 2; ks++) {
            bf16x8 af[4];
            int kb = ks * 4 + (lane >> 4);
            int arow_f = wm + (lane & 15);
#pragma unroll
            for (int sm = 0; sm < 4; sm++)
                af[sm] = *(const bf16x8*)&As8[(kb * 128 + arow_f + sm * 16) * 8];
#pragma unroll
            for (int sn = 0; sn < 4; sn++) {
                int ncol = wn + sn * 16 + (lane & 15);
                bf16x8 bdf = *(const bf16x8*)&Bd_s[(kb * 128 + ncol) * 8];
#pragma unroll
                for (int sm = 0; sm < 4; sm++)
                    acc[sm][sn] = __builtin_amdgcn_mfma_f32_16x16x32_bf16(af[sm], bdf, acc[sm][sn], 0, 0, 0);
            }
        }
    }
    int rbase = wm + ((lane >> 4) << 2);
    int cbase = wn + (lane & 15);
#pragma unroll
    for (int sm = 0; sm < 4; sm++) {
#pragma unroll
        for (int r = 0; r < 4; r++) {
            int pos = m0 + rbase + sm * 16 + r;
            if (pos < ne) {
                size_t ob = (size_t)(abase[e] + pos) * D_MODEL;
#pragma unroll
                for (int sn = 0; sn < 4; sn++) {
                    int col = n0 + cbase + sn * 16;
                    outp[ob + col] = acc[sm][sn][r] + bd[e * D_MODEL + col];
                }
            }
        }
    }
}

// ---------------- combine: y[t] = w0*outp[slot0] + w1*outp[slot1] ----------------
__global__ void k_combine(const float* __restrict__ outp, const int* __restrict__ slotpk,
                          const float* __restrict__ wtok, const int* __restrict__ abase,
                          float* __restrict__ y)
{
    int idx = blockIdx.x * 256 + threadIdx.x;   // 524288 float4s
    int t = idx >> 8, j = idx & 255;
    int sp0 = slotpk[t * 2 + 0], sp1 = slotpk[t * 2 + 1];
    float w0 = wtok[t * 2 + 0], w1 = wtok[t * 2 + 1];
    size_t s0 = (size_t)abase[sp0 >> 16] + (sp0 & 0xffff);
    size_t s1 = (size_t)abase[sp1 >> 16] + (sp1 & 0xffff);
    float4 a = ((const float4*)outp)[s0 * (D_MODEL / 4) + j];
    float4 b = ((const float4*)outp)[s1 * (D_MODEL / 4) + j];
    float4 o;
    o.x = w0 * a.x + w1 * b.x;
    o.y = w0 * a.y + w1 * b.y;
    o.z = w0 * a.z + w1 * b.z;
    o.w = w0 * a.w + w1 * b.w;
    ((float4*)y)[idx] = o;
}

extern "C" void kernel_launch(void* const* d_in, const int* in_sizes, int n_in,
                              void* d_out, int out_size, void* d_ws, size_t ws_size,
                              hipStream_t stream)
{
    const float* x  = (const float*)d_in[0];
    const float* gw = (const float*)d_in[1];
    const float* gb = (const float*)d_in[2];
    const float* Wg = (const float*)d_in[3];
    const float* bg = (const float*)d_in[4];
    const float* Wu = (const float*)d_in[5];
    const float* bu = (const float*)d_in[6];
    const float* Wd = (const float*)d_in[7];
    const float* bd = (const float*)d_in[8];
    float* y = (float*)d_out;
    float* loss_out = y + (size_t)T_TOK * D_MODEL;

    char* ws = (char*)d_ws;
    int*    cnt     = (int*)(ws + 0);             // 8 ints   [zeroed]
    float*  probsum = (float*)(ws + 32);          // 8 floats [zeroed]
    int*    abase   = (int*)(ws + 64);            // 8 ints (128-aligned bases)
    int*    tiletab = (int*)(ws + 96);            // MAXTILES ints
    int*    slotpk  = (int*)(ws + 512);           // 4096 ints
    float*  wtok    = (float*)(ws + 16896);       // 4096 floats
    int*    tok     = (int*)(ws + 33280);         // 8*2048 ints (ends 98816)
    ushort* xb      = (ushort*)(ws + 131072);     // 2M bf16 = 4 MB
    ushort* Wgt     = (ushort*)(ws + 4325376);    // 33.55 MB tiled bf16
    ushort* Wut     = (ushort*)(ws + 37879808);   // 33.55 MB
    ushort* Wdt     = (ushort*)(ws + 71434240);   // 33.55 MB
    ushort* h_t     = (ushort*)(ws + 104988672);  // 40 tiles * 32 kt * 16KB = 20.97 MB
    float*  outp    = (float*)(ws + 125960192);   // 5120*1024 fp32 = 20.97 MB
    // total ws use: ~140.1 MB

    hipMemsetAsync(d_ws, 0, 64, stream);
    k_prep_w<<<dim3(2048, 3), dim3(256), 0, stream>>>(Wg, Wu, Wd, Wgt, Wut, Wdt);
    k_convert_x<<<dim3(2048), dim3(256), 0, stream>>>(x, xb);
    k_router<<<dim3(512), dim3(256), 0, stream>>>(x, gw, gb, cnt, probsum, tok, slotpk, wtok);
    k_base_loss<<<dim3(1), dim3(64), 0, stream>>>(cnt, probsum, abase, tiletab, loss_out);
    k_expert_gu<<<dim3(MAXTILES, 16), dim3(256), 0, stream>>>(Wgt, Wut, bg, bu, xb, cnt, abase, tiletab, tok, h_t);
    k_expert_down<<<dim3(MAXTILES, 8), dim3(256), 0, stream>>>(Wdt, bd, h_t, cnt, abase, tiletab, outp);
    k_combine<<<dim3(2048), dim3(256), 0, stream>>>(outp, slotpk, wtok, abase, y);
}

// Round 4
// 398.652 us; speedup vs baseline: 4.9863x; 1.5603x over previous
//
#include <hip/hip_runtime.h>
#include <hip/hip_bf16.h>

// MoE SwiGLU MLP, sparse top-2 path.
// T=2048 tokens, D_MODEL=1024, D_FF=2048, E=8 experts, K=2.
// R3: router rewritten with block-level aggregation — LDS atomics for
//     per-block cnt/probsum + local slot, 16 global atomics per block
//     (was 10 per token, all on ONE cacheline => ~250us of serialization).
//     cnt/probsum now on separate 128B lines. Dot-product loads re-indexed
//     [q*64+lane]: coalesced x reads, uniform LDS banking (was 2-bank).

#define D_MODEL 1024
#define D_FF    2048
#define N_EXP   8
#define T_TOK   2048
#define MAXTILES 40   // sum_e ceil(cnt_e/128) <= 32+7 < 40

typedef __attribute__((ext_vector_type(8))) short bf16x8;
typedef __attribute__((ext_vector_type(8))) ushort u16x8;
typedef __attribute__((ext_vector_type(4))) float f32x4;

__device__ __forceinline__ ushort f2bf(float f) {
    union { float f; unsigned u; } c; c.f = f;
    unsigned u = c.u;
    return (ushort)((u + 0x7fffu + ((u >> 16) & 1u)) >> 16);  // RTNE
}

__device__ __forceinline__ void glds16(const void* g, void* l) {
    __builtin_amdgcn_global_load_lds(
        (const __attribute__((address_space(1))) unsigned int*)g,
        (__attribute__((address_space(3))) unsigned int*)l, 16, 0, 0);
}

// ---------------- x fp32 -> bf16 ----------------
__global__ void k_convert_x(const float* __restrict__ x, ushort* __restrict__ xb) {
    int idx = blockIdx.x * 256 + threadIdx.x;          // 524288 float4s
    float4 v = ((const float4*)x)[idx];
    ushort4 o;
    o.x = f2bf(v.x); o.y = f2bf(v.y); o.z = f2bf(v.z); o.w = f2bf(v.w);
    ((ushort4*)xb)[idx] = o;
}

// ---------------- weight prep: fp32 -> bf16, tiled k-inner-8 16KB blocks ----------------
// Tile = 64 k x 128 n. Layout within tile: [(kb)*128 + ncol]*8 + ko, k = kb*8+ko.
// Wg/Wu: (e, nt 0..15, kt 0..15), N=2048, K=1024. Wd: (e, nt 0..7, kt 0..31), N=1024, K=2048.
__global__ __launch_bounds__(256) void k_prep_w(
    const float* __restrict__ Wg, const float* __restrict__ Wu, const float* __restrict__ Wd,
    ushort* __restrict__ Wgt, ushort* __restrict__ Wut, ushort* __restrict__ Wdt)
{
    int t = blockIdx.x;          // 0..2047 (tile linear index == output block index)
    int which = blockIdx.y;      // 0=Wg 1=Wu 2=Wd
    const float* src; ushort* dst; int N, K, nt, kt;
    int e = t >> 8;
    if (which == 2) { src = Wd; dst = Wdt; N = 1024; K = 2048; nt = (t >> 5) & 7;  kt = t & 31; }
    else            { src = (which ? Wu : Wg); dst = (which ? Wut : Wgt); N = 2048; K = 1024; nt = (t >> 4) & 15; kt = t & 15; }

    int tid = threadIdx.x;
    int ncol = tid & 127, kbh = (tid >> 7) * 4;
    const float* colp = src + (size_t)e * K * N + (size_t)(kt * 64) * N + nt * 128 + ncol;
    ushort* dtile = dst + (size_t)t * 8192;
#pragma unroll
    for (int i = 0; i < 4; i++) {
        int kb = kbh + i;
        const float* p = colp + (size_t)(kb * 8) * N;
        u16x8 o;
#pragma unroll
        for (int j = 0; j < 8; j++) o[j] = f2bf(p[(size_t)j * N]);
        *(u16x8*)&dtile[(kb * 128 + ncol) * 8] = o;
    }
}

// ---------------- router: 64 blocks x 32 tokens, block-aggregated atomics ----------------
__global__ __launch_bounds__(256) void k_router(
    const float* __restrict__ x, const float* __restrict__ gw, const float* __restrict__ gb,
    int* cnt, float* probsum, int* tok, int* slotpk, float* wtok)
{
    __shared__ float gws[N_EXP * D_MODEL];   // 32 KB
    __shared__ float ps_s[N_EXP];
    __shared__ int   bc_s[N_EXP];
    __shared__ int   gb_s[N_EXP];
    __shared__ int   a_e[64];                // 32 tokens x 2 assignments
    __shared__ int   a_lp[64];

    int tid = threadIdx.x;
    for (int i = tid; i < N_EXP * D_MODEL / 4; i += 256)
        ((float4*)gws)[i] = ((const float4*)gw)[i];
    if (tid < N_EXP) { ps_s[tid] = 0.f; bc_s[tid] = 0; }
    __syncthreads();

    int wave = tid >> 6, lane = tid & 63;

    for (int it = 0; it < 8; it++) {
        int tb = it * 4 + wave;                      // token-in-block
        int t = blockIdx.x * 32 + tb;
        const float4* xr = (const float4*)(x + (size_t)t * D_MODEL);

        float acc[N_EXP];
#pragma unroll
        for (int e = 0; e < N_EXP; e++) acc[e] = 0.f;
#pragma unroll
        for (int q = 0; q < 4; q++) {
            int idx = q * 64 + lane;                 // coalesced + uniform banking
            float4 xv = xr[idx];
#pragma unroll
            for (int e = 0; e < N_EXP; e++) {
                float4 gv = ((const float4*)(gws + e * D_MODEL))[idx];
                acc[e] += xv.x * gv.x + xv.y * gv.y + xv.z * gv.z + xv.w * gv.w;
            }
        }
#pragma unroll
        for (int off = 32; off > 0; off >>= 1) {
#pragma unroll
            for (int e = 0; e < N_EXP; e++) acc[e] += __shfl_xor(acc[e], off, 64);
        }
        if (lane == 0) {
            float l[N_EXP], m = -1e30f;
#pragma unroll
            for (int e = 0; e < N_EXP; e++) { l[e] = acc[e] + gb[e]; m = fmaxf(m, l[e]); }
            float p[N_EXP], s = 0.f;
#pragma unroll
            for (int e = 0; e < N_EXP; e++) { p[e] = expf(l[e] - m); s += p[e]; }
            float inv = 1.f / s;
#pragma unroll
            for (int e = 0; e < N_EXP; e++) { p[e] *= inv; atomicAdd(&ps_s[e], p[e]); }
            // top-2, lowest index wins ties (matches lax.top_k)
            int i0 = 0; float v0 = p[0];
#pragma unroll
            for (int e = 1; e < N_EXP; e++) if (p[e] > v0) { v0 = p[e]; i0 = e; }
            int i1 = -1; float v1 = -1.f;
#pragma unroll
            for (int e = 0; e < N_EXP; e++) if (e != i0 && p[e] > v1) { v1 = p[e]; i1 = e; }
            float winv = 1.f / (v0 + v1);
            int lp0 = atomicAdd(&bc_s[i0], 1);
            int lp1 = atomicAdd(&bc_s[i1], 1);
            a_e[tb * 2 + 0] = i0; a_lp[tb * 2 + 0] = lp0;
            a_e[tb * 2 + 1] = i1; a_lp[tb * 2 + 1] = lp1;
            wtok[t * 2 + 0] = v0 * winv;
            wtok[t * 2 + 1] = v1 * winv;
        }
    }
    __syncthreads();
    if (tid < N_EXP) {
        gb_s[tid] = atomicAdd(&cnt[tid], bc_s[tid]);
        atomicAdd(&probsum[tid], ps_s[tid]);
    }
    __syncthreads();
    if (tid < 64) {
        int tb = tid >> 1, k = tid & 1;
        int t = blockIdx.x * 32 + tb;
        int e = a_e[tid];
        int slot = gb_s[e] + a_lp[tid];
        tok[e * T_TOK + slot] = t;
        slotpk[t * 2 + k] = (e << 16) | slot;
    }
}

// ---------------- 128-aligned expert bases + tile table + balance loss ----------------
__global__ void k_base_loss(const int* __restrict__ cnt, const float* __restrict__ probsum,
                            int* abase, int* tile, float* loss_out)
{
    if (threadIdx.x == 0 && blockIdx.x == 0) {
        int b = 0, nt = 0;
        float loss = 0.f;
        for (int e = 0; e < N_EXP; e++) {
            abase[e] = b;
            for (int m0 = 0; m0 < cnt[e]; m0 += 128)
                tile[nt++] = (e << 16) | m0;
            b += ((cnt[e] + 127) >> 7) * 128;           // capacity-aligned
            float mean = probsum[e] * (1.0f / T_TOK);
            loss += 0.125f * (logf(0.125f) - logf(mean + 1e-9f));
        }
        for (; nt < MAXTILES; nt++) tile[nt] = -1;
        *loss_out = loss;
    }
}

// ---------------- stage A: h = silu(x@Wg + bg) * (x@Wu + bu) ----------------
// 128x128 tile, BK=64, 4 waves, dual accumulators. B via global_load_lds from
// pre-tiled weights; A gathered (tok) with uint4 copies; h written tiled.
__global__ __launch_bounds__(256, 2) void k_expert_gu(
    const ushort* __restrict__ Wgt, const ushort* __restrict__ Wut,
    const float* __restrict__ bg, const float* __restrict__ bu,
    const ushort* __restrict__ xb, const int* __restrict__ cnt,
    const int* __restrict__ abase, const int* __restrict__ tile,
    const int* __restrict__ tok, ushort* __restrict__ h_t)
{
    int ti = tile[blockIdx.x];
    if (ti < 0) return;                       // contiguous tail only
    int e = ti >> 16, m0 = ti & 0xffff;
    int ne = cnt[e];
    int nt = blockIdx.y;                      // 0..15
    int n0 = nt * 128;
    int stile = (abase[e] >> 7) + (m0 >> 7);  // global aligned slot-tile

    __shared__ __align__(16) ushort As[128 * 88];     // stride 88: 16B aligned, 2-way banks
    __shared__ __align__(16) ushort Bg_s[8192];       // k-inner-8 image (16KB)
    __shared__ __align__(16) ushort Bu_s[8192];

    int tid = threadIdx.x;
    int lane = tid & 63, wave = tid >> 6;
    int wm = (wave & 1) * 64, wn = (wave >> 1) * 64;

    // A staging: thread -> (row, k-half)
    int arow = tid >> 1;
    int akh = (tid & 1) * 32;
    int atok = tok[e * T_TOK + min(m0 + arow, ne - 1)];
    const ushort* xrow = xb + (size_t)atok * D_MODEL;

    // B tile bases (16KB per kt)
    const char* gbase = (const char*)(Wgt + (size_t)(e * 16 + nt) * 16 * 8192);
    const char* ubase = (const char*)(Wut + (size_t)(e * 16 + nt) * 16 * 8192);
    int goff = tid * 16;                      // per-lane global byte offset in tile
    int loff = (tid >> 6) * 1024;             // wave-uniform LDS byte offset

    f32x4 accg[4][4], accu[4][4];
#pragma unroll
    for (int i = 0; i < 4; i++)
#pragma unroll
        for (int j = 0; j < 4; j++) {
            accg[i][j] = (f32x4){0.f, 0.f, 0.f, 0.f};
            accu[i][j] = (f32x4){0.f, 0.f, 0.f, 0.f};
        }

    for (int kt = 0; kt < D_MODEL / 64; kt++) {
        __syncthreads();
        // A tile: bf16 gather copy, 16B chunks
#pragma unroll
        for (int q = 0; q < 4; q++)
            *(uint4*)&As[arow * 88 + akh + q * 8] = *(const uint4*)&xrow[kt * 64 + akh + q * 8];
        // B tiles: direct-to-LDS block copy (16KB each)
        const char* gsrc = gbase + kt * 16384;
        const char* usrc = ubase + kt * 16384;
#pragma unroll
        for (int q = 0; q < 4; q++) {
            glds16(gsrc + q * 4096 + goff, (char*)Bg_s + q * 4096 + loff);
            glds16(usrc + q * 4096 + goff, (char*)Bu_s + q * 4096 + loff);
        }
        __syncthreads();
        // compute
#pragma unroll
        for (int ks = 0; ks < 2; ks++) {
            bf16x8 af[4];
            int arow_f = wm + (lane & 15);
            int akb = ks * 32 + (lane >> 4) * 8;
#pragma unroll
            for (int sm = 0; sm < 4; sm++)
                af[sm] = *(const bf16x8*)&As[(arow_f + sm * 16) * 88 + akb];
            int bkb = ks * 4 + (lane >> 4);
#pragma unroll
            for (int sn = 0; sn < 4; sn++) {
                int ncol = wn + sn * 16 + (lane & 15);
                bf16x8 bgf = *(const bf16x8*)&Bg_s[(bkb * 128 + ncol) * 8];
                bf16x8 buf = *(const bf16x8*)&Bu_s[(bkb * 128 + ncol) * 8];
#pragma unroll
                for (int sm = 0; sm < 4; sm++) {
                    accg[sm][sn] = __builtin_amdgcn_mfma_f32_16x16x32_bf16(af[sm], bgf, accg[sm][sn], 0, 0, 0);
                    accu[sm][sn] = __builtin_amdgcn_mfma_f32_16x16x32_bf16(af[sm], buf, accu[sm][sn], 0, 0, 0);
                }
            }
        }
    }
    // epilogue: silu(g)*u -> h_t (bf16, tiled k-inner-8 for stage B's A-operand)
    int rbase = wm + ((lane >> 4) << 2);
    int cbase = wn + (lane & 15);
    size_t tbase = (size_t)stile * 32 * 8192;
#pragma unroll
    for (int sm = 0; sm < 4; sm++) {
#pragma unroll
        for (int r = 0; r < 4; r++) {
            int pos = m0 + rbase + sm * 16 + r;
            if (pos < ne) {
                int row = pos & 127;
#pragma unroll
                for (int sn = 0; sn < 4; sn++) {
                    int col = n0 + cbase + sn * 16;
                    float g = accg[sm][sn][r] + bg[e * D_FF + col];
                    float u = accu[sm][sn][r] + bu[e * D_FF + col];
                    float hv = (g / (1.f + expf(-g))) * u;
                    int ktb = col >> 6, kb = (col >> 3) & 7, ko = col & 7;
                    h_t[tbase + (size_t)ktb * 8192 + (kb * 128 + row) * 8 + ko] = f2bf(hv);
                }
            }
        }
    }
}

// ---------------- stage B: outp = h @ Wd + bd (both operands via global_load_lds) ----------------
__global__ __launch_bounds__(256, 2) void k_expert_down(
    const ushort* __restrict__ Wdt, const float* __restrict__ bd,
    const ushort* __restrict__ h_t, const int* __restrict__ cnt,
    const int* __restrict__ abase, const int* __restrict__ tile,
    float* __restrict__ outp)
{
    int ti = tile[blockIdx.x];
    if (ti < 0) return;
    int e = ti >> 16, m0 = ti & 0xffff;
    int ne = cnt[e];
    int nt = blockIdx.y;                      // 0..7
    int n0 = nt * 128;
    int stile = (abase[e] >> 7) + (m0 >> 7);

    __shared__ __align__(16) ushort As8[8192];        // k-inner-8 image (16KB)
    __shared__ __align__(16) ushort Bd_s[8192];

    int tid = threadIdx.x;
    int lane = tid & 63, wave = tid >> 6;
    int wm = (wave & 1) * 64, wn = (wave >> 1) * 64;

    const char* hbase = (const char*)(h_t + (size_t)stile * 32 * 8192);
    const char* dbase = (const char*)(Wdt + (size_t)(e * 8 + nt) * 32 * 8192);
    int goff = tid * 16;
    int loff = (tid >> 6) * 1024;

    f32x4 acc[4][4];
#pragma unroll
    for (int i = 0; i < 4; i++)
#pragma unroll
        for (int j = 0; j < 4; j++) acc[i][j] = (f32x4){0.f, 0.f, 0.f, 0.f};

    for (int kt = 0; kt < D_FF / 64; kt++) {
        __syncthreads();
        const char* asrc = hbase + kt * 16384;
        const char* bsrc = dbase + kt * 16384;
#pragma unroll
        for (int q = 0; q < 4; q++) {
            glds16(asrc + q * 4096 + goff, (char*)As8 + q * 4096 + loff);
            glds16(bsrc + q * 4096 + goff, (char*)Bd_s + q * 4096 + loff);
        }
        __syncthreads();
#pragma unroll
        for (int ks = 0; ks < 2; ks++) {
            bf16x8 af[4];
            int kb = ks * 4 + (lane >> 4);
            int arow_f = wm + (lane & 15);
#pragma unroll
            for (int sm = 0; sm < 4; sm++)
                af[sm] = *(const bf16x8*)&As8[(kb * 128 + arow_f + sm * 16) * 8];
#pragma unroll
            for (int sn = 0; sn < 4; sn++) {
                int ncol = wn + sn * 16 + (lane & 15);
                bf16x8 bdf = *(const bf16x8*)&Bd_s[(kb * 128 + ncol) * 8];
#pragma unroll
                for (int sm = 0; sm < 4; sm++)
                    acc[sm][sn] = __builtin_amdgcn_mfma_f32_16x16x32_bf16(af[sm], bdf, acc[sm][sn], 0, 0, 0);
            }
        }
    }
    int rbase = wm + ((lane >> 4) << 2);
    int cbase = wn + (lane & 15);
#pragma unroll
    for (int sm = 0; sm < 4; sm++) {
#pragma unroll
        for (int r = 0; r < 4; r++) {
            int pos = m0 + rbase + sm * 16 + r;
            if (pos < ne) {
                size_t ob = (size_t)(abase[e] + pos) * D_MODEL;
#pragma unroll
                for (int sn = 0; sn < 4; sn++) {
                    int col = n0 + cbase + sn * 16;
                    outp[ob + col] = acc[sm][sn][r] + bd[e * D_MODEL + col];
                }
            }
        }
    }
}

// ---------------- combine: y[t] = w0*outp[slot0] + w1*outp[slot1] ----------------
__global__ void k_combine(const float* __restrict__ outp, const int* __restrict__ slotpk,
                          const float* __restrict__ wtok, const int* __restrict__ abase,
                          float* __restrict__ y)
{
    int idx = blockIdx.x * 256 + threadIdx.x;   // 524288 float4s
    int t = idx >> 8, j = idx & 255;
    int sp0 = slotpk[t * 2 + 0], sp1 = slotpk[t * 2 + 1];
    float w0 = wtok[t * 2 + 0], w1 = wtok[t * 2 + 1];
    size_t s0 = (size_t)abase[sp0 >> 16] + (sp0 & 0xffff);
    size_t s1 = (size_t)abase[sp1 >> 16] + (sp1 & 0xffff);
    float4 a = ((const float4*)outp)[s0 * (D_MODEL / 4) + j];
    float4 b = ((const float4*)outp)[s1 * (D_MODEL / 4) + j];
    float4 o;
    o.x = w0 * a.x + w1 * b.x;
    o.y = w0 * a.y + w1 * b.y;
    o.z = w0 * a.z + w1 * b.z;
    o.w = w0 * a.w + w1 * b.w;
    ((float4*)y)[idx] = o;
}

extern "C" void kernel_launch(void* const* d_in, const int* in_sizes, int n_in,
                              void* d_out, int out_size, void* d_ws, size_t ws_size,
                              hipStream_t stream)
{
    const float* x  = (const float*)d_in[0];
    const float* gw = (const float*)d_in[1];
    const float* gb = (const float*)d_in[2];
    const float* Wg = (const float*)d_in[3];
    const float* bg = (const float*)d_in[4];
    const float* Wu = (const float*)d_in[5];
    const float* bu = (const float*)d_in[6];
    const float* Wd = (const float*)d_in[7];
    const float* bd = (const float*)d_in[8];
    float* y = (float*)d_out;
    float* loss_out = y + (size_t)T_TOK * D_MODEL;

    char* ws = (char*)d_ws;
    int*    cnt     = (int*)(ws + 0);             // 8 ints   [zeroed]  (own 128B line)
    float*  probsum = (float*)(ws + 128);         // 8 floats [zeroed]  (own 128B line)
    int*    abase   = (int*)(ws + 256);           // 8 ints (128-aligned bases)
    int*    tiletab = (int*)(ws + 320);           // MAXTILES ints
    int*    slotpk  = (int*)(ws + 512);           // 4096 ints
    float*  wtok    = (float*)(ws + 16896);       // 4096 floats
    int*    tok     = (int*)(ws + 33280);         // 8*2048 ints (ends 98816)
    ushort* xb      = (ushort*)(ws + 131072);     // 2M bf16 = 4 MB
    ushort* Wgt     = (ushort*)(ws + 4325376);    // 33.55 MB tiled bf16
    ushort* Wut     = (ushort*)(ws + 37879808);   // 33.55 MB
    ushort* Wdt     = (ushort*)(ws + 71434240);   // 33.55 MB
    ushort* h_t     = (ushort*)(ws + 104988672);  // 40 tiles * 32 kt * 16KB = 20.97 MB
    float*  outp    = (float*)(ws + 125960192);   // 5120*1024 fp32 = 20.97 MB
    // total ws use: ~140.1 MB

    hipMemsetAsync(d_ws, 0, 256, stream);
    k_prep_w<<<dim3(2048, 3), dim3(256), 0, stream>>>(Wg, Wu, Wd, Wgt, Wut, Wdt);
    k_convert_x<<<dim3(2048), dim3(256), 0, stream>>>(x, xb);
    k_router<<<dim3(64), dim3(256), 0, stream>>>(x, gw, gb, cnt, probsum, tok, slotpk, wtok);
    k_base_loss<<<dim3(1), dim3(64), 0, stream>>>(cnt, probsum, abase, tiletab, loss_out);
    k_expert_gu<<<dim3(MAXTILES, 16), dim3(256), 0, stream>>>(Wgt, Wut, bg, bu, xb, cnt, abase, tiletab, tok, h_t);
    k_expert_down<<<dim3(MAXTILES, 8), dim3(256), 0, stream>>>(Wdt, bd, h_t, cnt, abase, tiletab, outp);
    k_combine<<<dim3(2048), dim3(256), 0, stream>>>(outp, slotpk, wtok, abase, y);
}

// Round 5
// 381.012 us; speedup vs baseline: 5.2171x; 1.0463x over previous
//
#include <hip/hip_runtime.h>
#include <hip/hip_bf16.h>

// MoE SwiGLU MLP, sparse top-2 path.
// T=2048 tokens, D_MODEL=1024, D_FF=2048, E=8 experts, K=2.
// R4: k_prep_w register-transpose rewrite — float4 reads along n (8 in flight),
//     in-register 8k x 4n transpose, 64B-contiguous u16x8 writes (was scalar
//     dword reads at 20 VGPRs => 2.3 TB/s). x->bf16 conversion folded into
//     k_router (it already reads all of x); k_convert_x removed.

#define D_MODEL 1024
#define D_FF    2048
#define N_EXP   8
#define T_TOK   2048
#define MAXTILES 40   // sum_e ceil(cnt_e/128) <= 32+7 < 40

typedef __attribute__((ext_vector_type(8))) short bf16x8;
typedef __attribute__((ext_vector_type(8))) ushort u16x8;
typedef __attribute__((ext_vector_type(4))) float f32x4;

__device__ __forceinline__ ushort f2bf(float f) {
    union { float f; unsigned u; } c; c.f = f;
    unsigned u = c.u;
    return (ushort)((u + 0x7fffu + ((u >> 16) & 1u)) >> 16);  // RTNE
}

__device__ __forceinline__ void glds16(const void* g, void* l) {
    __builtin_amdgcn_global_load_lds(
        (const __attribute__((address_space(1))) unsigned int*)g,
        (__attribute__((address_space(3))) unsigned int*)l, 16, 0, 0);
}

// ---------------- weight prep: fp32 -> bf16, tiled k-inner-8 16KB blocks ----------------
// Tile = 64 k x 128 n. Layout within tile: [(kb)*128 + ncol]*8 + ko, k = kb*8+ko.
// Wg/Wu: (e, nt 0..15, kt 0..15), N=2048, K=1024. Wd: (e, nt 0..7, kt 0..31), N=1024, K=2048.
// Thread owns (kb = tid>>5, 4 ncols at c4 = tid&31): 8 float4 loads along n,
// register transpose, 4 contiguous u16x8 (64 B) writes.
__global__ __launch_bounds__(256) void k_prep_w(
    const float* __restrict__ Wg, const float* __restrict__ Wu, const float* __restrict__ Wd,
    ushort* __restrict__ Wgt, ushort* __restrict__ Wut, ushort* __restrict__ Wdt)
{
    int t = blockIdx.x;          // 0..2047 (tile linear index == output block index)
    int which = blockIdx.y;      // 0=Wg 1=Wu 2=Wd
    const float* src; ushort* dst; int N, nt, kt;
    int e = t >> 8;
    if (which == 2) { src = Wd; dst = Wdt; N = 1024; nt = (t >> 5) & 7;  kt = t & 31; }
    else            { src = (which ? Wu : Wg); dst = (which ? Wut : Wgt); N = 2048; nt = (t >> 4) & 15; kt = t & 15; }

    int tid = threadIdx.x;
    int kb = tid >> 5;                 // 0..7
    int c4 = (tid & 31) * 4;           // ncol base, 0..124
    const float* p0 = src + (size_t)(e * (N == 2048 ? 1024 : 2048) /*K*/) * 0; // placeholder avoid
    // base pointer: e*K*N + (kt*64 + kb*8)*N + nt*128 + c4
    size_t K = (N == 2048) ? 1024 : 2048;
    const float* p = src + (size_t)e * K * N + (size_t)(kt * 64 + kb * 8) * N + nt * 128 + c4;

    float4 v[8];
#pragma unroll
    for (int j = 0; j < 8; j++)
        v[j] = *(const float4*)(p + (size_t)j * N);

    u16x8 o0, o1, o2, o3;
#pragma unroll
    for (int j = 0; j < 8; j++) {
        o0[j] = f2bf(v[j].x);
        o1[j] = f2bf(v[j].y);
        o2[j] = f2bf(v[j].z);
        o3[j] = f2bf(v[j].w);
    }
    ushort* d = dst + (size_t)t * 8192 + (size_t)(kb * 128 + c4) * 8;
    *(u16x8*)(d + 0)  = o0;
    *(u16x8*)(d + 8)  = o1;
    *(u16x8*)(d + 16) = o2;
    *(u16x8*)(d + 24) = o3;
}

// ---------------- router: 64 blocks x 32 tokens, block-aggregated atomics ----------------
// Also emits xb (bf16 copy of x) since it reads every x element anyway.
__global__ __launch_bounds__(256) void k_router(
    const float* __restrict__ x, const float* __restrict__ gw, const float* __restrict__ gb,
    int* cnt, float* probsum, int* tok, int* slotpk, float* wtok,
    ushort* __restrict__ xb)
{
    __shared__ float gws[N_EXP * D_MODEL];   // 32 KB
    __shared__ float ps_s[N_EXP];
    __shared__ int   bc_s[N_EXP];
    __shared__ int   gb_s[N_EXP];
    __shared__ int   a_e[64];                // 32 tokens x 2 assignments
    __shared__ int   a_lp[64];

    int tid = threadIdx.x;
    for (int i = tid; i < N_EXP * D_MODEL / 4; i += 256)
        ((float4*)gws)[i] = ((const float4*)gw)[i];
    if (tid < N_EXP) { ps_s[tid] = 0.f; bc_s[tid] = 0; }
    __syncthreads();

    int wave = tid >> 6, lane = tid & 63;

    for (int it = 0; it < 8; it++) {
        int tb = it * 4 + wave;                      // token-in-block
        int t = blockIdx.x * 32 + tb;
        const float4* xr = (const float4*)(x + (size_t)t * D_MODEL);
        ushort* xbr = xb + (size_t)t * D_MODEL;

        float acc[N_EXP];
#pragma unroll
        for (int e = 0; e < N_EXP; e++) acc[e] = 0.f;
#pragma unroll
        for (int q = 0; q < 4; q++) {
            int idx = q * 64 + lane;                 // coalesced + uniform banking
            float4 xv = xr[idx];
            ushort4 xc;
            xc.x = f2bf(xv.x); xc.y = f2bf(xv.y); xc.z = f2bf(xv.z); xc.w = f2bf(xv.w);
            *(ushort4*)&xbr[idx * 4] = xc;
#pragma unroll
            for (int e = 0; e < N_EXP; e++) {
                float4 gv = ((const float4*)(gws + e * D_MODEL))[idx];
                acc[e] += xv.x * gv.x + xv.y * gv.y + xv.z * gv.z + xv.w * gv.w;
            }
        }
#pragma unroll
        for (int off = 32; off > 0; off >>= 1) {
#pragma unroll
            for (int e = 0; e < N_EXP; e++) acc[e] += __shfl_xor(acc[e], off, 64);
        }
        if (lane == 0) {
            float l[N_EXP], m = -1e30f;
#pragma unroll
            for (int e = 0; e < N_EXP; e++) { l[e] = acc[e] + gb[e]; m = fmaxf(m, l[e]); }
            float p[N_EXP], s = 0.f;
#pragma unroll
            for (int e = 0; e < N_EXP; e++) { p[e] = expf(l[e] - m); s += p[e]; }
            float inv = 1.f / s;
#pragma unroll
            for (int e = 0; e < N_EXP; e++) { p[e] *= inv; atomicAdd(&ps_s[e], p[e]); }
            // top-2, lowest index wins ties (matches lax.top_k)
            int i0 = 0; float v0 = p[0];
#pragma unroll
            for (int e = 1; e < N_EXP; e++) if (p[e] > v0) { v0 = p[e]; i0 = e; }
            int i1 = -1; float v1 = -1.f;
#pragma unroll
            for (int e = 0; e < N_EXP; e++) if (e != i0 && p[e] > v1) { v1 = p[e]; i1 = e; }
            float winv = 1.f / (v0 + v1);
            int lp0 = atomicAdd(&bc_s[i0], 1);
            int lp1 = atomicAdd(&bc_s[i1], 1);
            a_e[tb * 2 + 0] = i0; a_lp[tb * 2 + 0] = lp0;
            a_e[tb * 2 + 1] = i1; a_lp[tb * 2 + 1] = lp1;
            wtok[t * 2 + 0] = v0 * winv;
            wtok[t * 2 + 1] = v1 * winv;
        }
    }
    __syncthreads();
    if (tid < N_EXP) {
        gb_s[tid] = atomicAdd(&cnt[tid], bc_s[tid]);
        atomicAdd(&probsum[tid], ps_s[tid]);
    }
    __syncthreads();
    if (tid < 64) {
        int tb = tid >> 1, k = tid & 1;
        int t = blockIdx.x * 32 + tb;
        int e = a_e[tid];
        int slot = gb_s[e] + a_lp[tid];
        tok[e * T_TOK + slot] = t;
        slotpk[t * 2 + k] = (e << 16) | slot;
    }
}

// ---------------- 128-aligned expert bases + tile table + balance loss ----------------
__global__ void k_base_loss(const int* __restrict__ cnt, const float* __restrict__ probsum,
                            int* abase, int* tile, float* loss_out)
{
    if (threadIdx.x == 0 && blockIdx.x == 0) {
        int b = 0, nt = 0;
        float loss = 0.f;
        for (int e = 0; e < N_EXP; e++) {
            abase[e] = b;
            for (int m0 = 0; m0 < cnt[e]; m0 += 128)
                tile[nt++] = (e << 16) | m0;
            b += ((cnt[e] + 127) >> 7) * 128;           // capacity-aligned
            float mean = probsum[e] * (1.0f / T_TOK);
            loss += 0.125f * (logf(0.125f) - logf(mean + 1e-9f));
        }
        for (; nt < MAXTILES; nt++) tile[nt] = -1;
        *loss_out = loss;
    }
}

// ---------------- stage A: h = silu(x@Wg + bg) * (x@Wu + bu) ----------------
// 128x128 tile, BK=64, 4 waves, dual accumulators. B via global_load_lds from
// pre-tiled weights; A gathered (tok) with uint4 copies; h written tiled.
__global__ __launch_bounds__(256, 2) void k_expert_gu(
    const ushort* __restrict__ Wgt, const ushort* __restrict__ Wut,
    const float* __restrict__ bg, const float* __restrict__ bu,
    const ushort* __restrict__ xb, const int* __restrict__ cnt,
    const int* __restrict__ abase, const int* __restrict__ tile,
    const int* __restrict__ tok, ushort* __restrict__ h_t)
{
    int ti = tile[blockIdx.x];
    if (ti < 0) return;                       // contiguous tail only
    int e = ti >> 16, m0 = ti & 0xffff;
    int ne = cnt[e];
    int nt = blockIdx.y;                      // 0..15
    int n0 = nt * 128;
    int stile = (abase[e] >> 7) + (m0 >> 7);  // global aligned slot-tile

    __shared__ __align__(16) ushort As[128 * 88];     // stride 88: 16B aligned, 2-way banks
    __shared__ __align__(16) ushort Bg_s[8192];       // k-inner-8 image (16KB)
    __shared__ __align__(16) ushort Bu_s[8192];

    int tid = threadIdx.x;
    int lane = tid & 63, wave = tid >> 6;
    int wm = (wave & 1) * 64, wn = (wave >> 1) * 64;

    // A staging: thread -> (row, k-half)
    int arow = tid >> 1;
    int akh = (tid & 1) * 32;
    int atok = tok[e * T_TOK + min(m0 + arow, ne - 1)];
    const ushort* xrow = xb + (size_t)atok * D_MODEL;

    // B tile bases (16KB per kt)
    const char* gbase = (const char*)(Wgt + (size_t)(e * 16 + nt) * 16 * 8192);
    const char* ubase = (const char*)(Wut + (size_t)(e * 16 + nt) * 16 * 8192);
    int goff = tid * 16;                      // per-lane global byte offset in tile
    int loff = (tid >> 6) * 1024;             // wave-uniform LDS byte offset

    f32x4 accg[4][4], accu[4][4];
#pragma unroll
    for (int i = 0; i < 4; i++)
#pragma unroll
        for (int j = 0; j < 4; j++) {
            accg[i][j] = (f32x4){0.f, 0.f, 0.f, 0.f};
            accu[i][j] = (f32x4){0.f, 0.f, 0.f, 0.f};
        }

    for (int kt = 0; kt < D_MODEL / 64; kt++) {
        __syncthreads();
        // A tile: bf16 gather copy, 16B chunks
#pragma unroll
        for (int q = 0; q < 4; q++)
            *(uint4*)&As[arow * 88 + akh + q * 8] = *(const uint4*)&xrow[kt * 64 + akh + q * 8];
        // B tiles: direct-to-LDS block copy (16KB each)
        const char* gsrc = gbase + kt * 16384;
        const char* usrc = ubase + kt * 16384;
#pragma unroll
        for (int q = 0; q < 4; q++) {
            glds16(gsrc + q * 4096 + goff, (char*)Bg_s + q * 4096 + loff);
            glds16(usrc + q * 4096 + goff, (char*)Bu_s + q * 4096 + loff);
        }
        __syncthreads();
        // compute
#pragma unroll
        for (int ks = 0; ks < 2; ks++) {
            bf16x8 af[4];
            int arow_f = wm + (lane & 15);
            int akb = ks * 32 + (lane >> 4) * 8;
#pragma unroll
            for (int sm = 0; sm < 4; sm++)
                af[sm] = *(const bf16x8*)&As[(arow_f + sm * 16) * 88 + akb];
            int bkb = ks * 4 + (lane >> 4);
#pragma unroll
            for (int sn = 0; sn < 4; sn++) {
                int ncol = wn + sn * 16 + (lane & 15);
                bf16x8 bgf = *(const bf16x8*)&Bg_s[(bkb * 128 + ncol) * 8];
                bf16x8 buf = *(const bf16x8*)&Bu_s[(bkb * 128 + ncol) * 8];
#pragma unroll
                for (int sm = 0; sm < 4; sm++) {
                    accg[sm][sn] = __builtin_amdgcn_mfma_f32_16x16x32_bf16(af[sm], bgf, accg[sm][sn], 0, 0, 0);
                    accu[sm][sn] = __builtin_amdgcn_mfma_f32_16x16x32_bf16(af[sm], buf, accu[sm][sn], 0, 0, 0);
                }
            }
        }
    }
    // epilogue: silu(g)*u -> h_t (bf16, tiled k-inner-8 for stage B's A-operand)
    int rbase = wm + ((lane >> 4) << 2);
    int cbase = wn + (lane & 15);
    size_t tbase = (size_t)stile * 32 * 8192;
#pragma unroll
    for (int sm = 0; sm < 4; sm++) {
#pragma unroll
        for (int r = 0; r < 4; r++) {
            int pos = m0 + rbase + sm * 16 + r;
            if (pos < ne) {
                int row = pos & 127;
#pragma unroll
                for (int sn = 0; sn < 4; sn++) {
                    int col = n0 + cbase + sn * 16;
                    float g = accg[sm][sn][r] + bg[e * D_FF + col];
                    float u = accu[sm][sn][r] + bu[e * D_FF + col];
                    float hv = (g / (1.f + expf(-g))) * u;
                    int ktb = col >> 6, kb = (col >> 3) & 7, ko = col & 7;
                    h_t[tbase + (size_t)ktb * 8192 + (kb * 128 + row) * 8 + ko] = f2bf(hv);
                }
            }
        }
    }
}

// ---------------- stage B: outp = h @ Wd + bd (both operands via global_load_lds) ----------------
__global__ __launch_bounds__(256, 2) void k_expert_down(
    const ushort* __restrict__ Wdt, const float* __restrict__ bd,
    const ushort* __restrict__ h_t, const int* __restrict__ cnt,
    const int* __restrict__ abase, const int* __restrict__ tile,
    float* __restrict__ outp)
{
    int ti = tile[blockIdx.x];
    if (ti < 0) return;
    int e = ti >> 16, m0 = ti & 0xffff;
    int ne = cnt[e];
    int nt = blockIdx.y;                      // 0..7
    int n0 = nt * 128;
    int stile = (abase[e] >> 7) + (m0 >> 7);

    __shared__ __align__(16) ushort As8[8192];        // k-inner-8 image (16KB)
    __shared__ __align__(16) ushort Bd_s[8192];

    int tid = threadIdx.x;
    int lane = tid & 63, wave = tid >> 6;
    int wm = (wave & 1) * 64, wn = (wave >> 1) * 64;

    const char* hbase = (const char*)(h_t + (size_t)stile * 32 * 8192);
    const char* dbase = (const char*)(Wdt + (size_t)(e * 8 + nt) * 32 * 8192);
    int goff = tid * 16;
    int loff = (tid >> 6) * 1024;

    f32x4 acc[4][4];
#pragma unroll
    for (int i = 0; i < 4; i++)
#pragma unroll
        for (int j = 0; j < 4; j++) acc[i][j] = (f32x4){0.f, 0.f, 0.f, 0.f};

    for (int kt = 0; kt < D_FF / 64; kt++) {
        __syncthreads();
        const char* asrc = hbase + kt * 16384;
        const char* bsrc = dbase + kt * 16384;
#pragma unroll
        for (int q = 0; q < 4; q++) {
            glds16(asrc + q * 4096 + goff, (char*)As8 + q * 4096 + loff);
            glds16(bsrc + q * 4096 + goff, (char*)Bd_s + q * 4096 + loff);
        }
        __syncthreads();
#pragma unroll
        for (int ks = 0; ks < 2; ks++) {
            bf16x8 af[4];
            int kb = ks * 4 + (lane >> 4);
            int arow_f = wm + (lane & 15);
#pragma unroll
            for (int sm = 0; sm < 4; sm++)
                af[sm] = *(const bf16x8*)&As8[(kb * 128 + arow_f + sm * 16) * 8];
#pragma unroll
            for (int sn = 0; sn < 4; sn++) {
                int ncol = wn + sn * 16 + (lane & 15);
                bf16x8 bdf = *(const bf16x8*)&Bd_s[(kb * 128 + ncol) * 8];
#pragma unroll
                for (int sm = 0; sm < 4; sm++)
                    acc[sm][sn] = __builtin_amdgcn_mfma_f32_16x16x32_bf16(af[sm], bdf, acc[sm][sn], 0, 0, 0);
            }
        }
    }
    int rbase = wm + ((lane >> 4) << 2);
    int cbase = wn + (lane & 15);
#pragma unroll
    for (int sm = 0; sm < 4; sm++) {
#pragma unroll
        for (int r = 0; r < 4; r++) {
            int pos = m0 + rbase + sm * 16 + r;
            if (pos < ne) {
                size_t ob = (size_t)(abase[e] + pos) * D_MODEL;
#pragma unroll
                for (int sn = 0; sn < 4; sn++) {
                    int col = n0 + cbase + sn * 16;
                    outp[ob + col] = acc[sm][sn][r] + bd[e * D_MODEL + col];
                }
            }
        }
    }
}

// ---------------- combine: y[t] = w0*outp[slot0] + w1*outp[slot1] ----------------
__global__ void k_combine(const float* __restrict__ outp, const int* __restrict__ slotpk,
                          const float* __restrict__ wtok, const int* __restrict__ abase,
                          float* __restrict__ y)
{
    int idx = blockIdx.x * 256 + threadIdx.x;   // 524288 float4s
    int t = idx >> 8, j = idx & 255;
    int sp0 = slotpk[t * 2 + 0], sp1 = slotpk[t * 2 + 1];
    float w0 = wtok[t * 2 + 0], w1 = wtok[t * 2 + 1];
    size_t s0 = (size_t)abase[sp0 >> 16] + (sp0 & 0xffff);
    size_t s1 = (size_t)abase[sp1 >> 16] + (sp1 & 0xffff);
    float4 a = ((const float4*)outp)[s0 * (D_MODEL / 4) + j];
    float4 b = ((const float4*)outp)[s1 * (D_MODEL / 4) + j];
    float4 o;
    o.x = w0 * a.x + w1 * b.x;
    o.y = w0 * a.y + w1 * b.y;
    o.z = w0 * a.z + w1 * b.z;
    o.w = w0 * a.w + w1 * b.w;
    ((float4*)y)[idx] = o;
}

extern "C" void kernel_launch(void* const* d_in, const int* in_sizes, int n_in,
                              void* d_out, int out_size, void* d_ws, size_t ws_size,
                              hipStream_t stream)
{
    const float* x  = (const float*)d_in[0];
    const float* gw = (const float*)d_in[1];
    const float* gb = (const float*)d_in[2];
    const float* Wg = (const float*)d_in[3];
    const float* bg = (const float*)d_in[4];
    const float* Wu = (const float*)d_in[5];
    const float* bu = (const float*)d_in[6];
    const float* Wd = (const float*)d_in[7];
    const float* bd = (const float*)d_in[8];
    float* y = (float*)d_out;
    float* loss_out = y + (size_t)T_TOK * D_MODEL;

    char* ws = (char*)d_ws;
    int*    cnt     = (int*)(ws + 0);             // 8 ints   [zeroed]  (own 128B line)
    float*  probsum = (float*)(ws + 128);         // 8 floats [zeroed]  (own 128B line)
    int*    abase   = (int*)(ws + 256);           // 8 ints (128-aligned bases)
    int*    tiletab = (int*)(ws + 320);           // MAXTILES ints
    int*    slotpk  = (int*)(ws + 512);           // 4096 ints
    float*  wtok    = (float*)(ws + 16896);       // 4096 floats
    int*    tok     = (int*)(ws + 33280);         // 8*2048 ints (ends 98816)
    ushort* xb      = (ushort*)(ws + 131072);     // 2M bf16 = 4 MB
    ushort* Wgt     = (ushort*)(ws + 4325376);    // 33.55 MB tiled bf16
    ushort* Wut     = (ushort*)(ws + 37879808);   // 33.55 MB
    ushort* Wdt     = (ushort*)(ws + 71434240);   // 33.55 MB
    ushort* h_t     = (ushort*)(ws + 104988672);  // 40 tiles * 32 kt * 16KB = 20.97 MB
    float*  outp    = (float*)(ws + 125960192);   // 5120*1024 fp32 = 20.97 MB
    // total ws use: ~140.1 MB

    hipMemsetAsync(d_ws, 0, 256, stream);
    k_prep_w<<<dim3(2048, 3), dim3(256), 0, stream>>>(Wg, Wu, Wd, Wgt, Wut, Wdt);
    k_router<<<dim3(64), dim3(256), 0, stream>>>(x, gw, gb, cnt, probsum, tok, slotpk, wtok, xb);
    k_base_loss<<<dim3(1), dim3(64), 0, stream>>>(cnt, probsum, abase, tiletab, loss_out);
    k_expert_gu<<<dim3(MAXTILES, 16), dim3(256), 0, stream>>>(Wgt, Wut, bg, bu, xb, cnt, abase, tiletab, tok, h_t);
    k_expert_down<<<dim3(MAXTILES, 8), dim3(256), 0, stream>>>(Wdt, bd, h_t, cnt, abase, tiletab, outp);
    k_combine<<<dim3(2048), dim3(256), 0, stream>>>(outp, slotpk, wtok, abase, y);
}